// Round 7
// baseline (890.052 us; speedup 1.0000x reference)
//
#include <hip/hip_runtime.h>

#define NN 100000
#define NE 1600000
#define HID 64
#define NL 3
#define BN_EPS 1e-5f
#define BSH 7
#define BNODES 128
#define NB 782                 // ceil(NN / BNODES)
#define BIN_CHUNK 16384
#define BIN_GRID ((NE + BIN_CHUNK - 1) / BIN_CHUNK)

__device__ __forceinline__ float bf2f(unsigned short u) {
    union { unsigned int i; float f; } v; v.i = ((unsigned int)u) << 16; return v.f;
}
__device__ __forceinline__ unsigned short f2bf(float f) {
    union { float f; unsigned int i; } v; v.f = f;
    unsigned int r = v.i + 0x7FFFu + ((v.i >> 16) & 1u);   // RNE
    return (unsigned short)(r >> 16);
}

// ---------------- input convert x f32 -> bf16 ----------------
__global__ void k_conv(const float* __restrict__ x, ushort* __restrict__ xb) {
    int i = blockIdx.x * blockDim.x + threadIdx.x;   // over NN*HID/4
    float4 v = ((const float4*)x)[i];
    ushort4 o;
    o.x = f2bf(v.x); o.y = f2bf(v.y); o.z = f2bf(v.z); o.w = f2bf(v.w);
    ((ushort4*)xb)[i] = o;
}

// ---------------- bucket histogram ----------------
__global__ void k_histB(const int* __restrict__ dst, int* __restrict__ ghist) {
    __shared__ int lh[NB];
    for (int i = threadIdx.x; i < NB; i += blockDim.x) lh[i] = 0;
    __syncthreads();
    int base = blockIdx.x * BIN_CHUNK;
    int end = min(base + BIN_CHUNK, NE);
    for (int e = base + threadIdx.x; e < end; e += blockDim.x)
        atomicAdd(&lh[dst[e] >> BSH], 1);
    __syncthreads();
    for (int i = threadIdx.x; i < NB; i += blockDim.x)
        if (lh[i]) atomicAdd(&ghist[i], lh[i]);
}

// ---------------- bucket scan (one block, NB <= 1024) ----------------
__global__ void k_scanB(const int* __restrict__ ghist, int* __restrict__ boffB,
                        int* __restrict__ gcur) {
    __shared__ int t[1024];
    int tid = threadIdx.x;
    int v = (tid < NB) ? ghist[tid] : 0;
    t[tid] = v;
    __syncthreads();
    for (int d = 1; d < 1024; d <<= 1) {
        int u = (tid >= d) ? t[tid - d] : 0;
        __syncthreads();
        t[tid] += u;
        __syncthreads();
    }
    if (tid < NB) { int ex = t[tid] - v; boffB[tid] = ex; gcur[tid] = ex; }
    if (tid == 0) boffB[NB] = NE;
}

// ---------------- binning: block-local hist -> bulk reserve -> write ----------------
__global__ void k_binB(const int* __restrict__ ei, const float* __restrict__ att,
                       int* __restrict__ gcur, int2* __restrict__ evb) {
    __shared__ int lh[NB];
    for (int i = threadIdx.x; i < NB; i += blockDim.x) lh[i] = 0;
    __syncthreads();
    int base = blockIdx.x * BIN_CHUNK;
    int end = min(base + BIN_CHUNK, NE);
    for (int e = base + threadIdx.x; e < end; e += blockDim.x)
        atomicAdd(&lh[ei[NE + e] >> BSH], 1);
    __syncthreads();
    for (int i = threadIdx.x; i < NB; i += blockDim.x) {
        int c = lh[i];
        lh[i] = c ? atomicAdd(&gcur[i], c) : 0;   // lh becomes running cursor
    }
    __syncthreads();
    for (int e = base + threadIdx.x; e < end; e += blockDim.x) {
        int d = ei[NE + e];
        int b = d >> BSH;
        int p = atomicAdd(&lh[b], 1);
        evb[p] = make_int2(ei[e] | ((d & (BNODES - 1)) << 17), __float_as_int(att[e]));
    }
}

// ------- pass 2: per-bucket exact CSR placement; also writes per-node offs -------
__global__ __launch_bounds__(256) void k_scatter2(const int2* __restrict__ evb,
                                                  const int* __restrict__ boffB,
                                                  int* __restrict__ offs,
                                                  int2* __restrict__ ev) {
    __shared__ int h[BNODES];
    __shared__ int cur[BNODES];
    int tid = threadIdx.x;
    int b = blockIdx.x;
    int node0 = b << BSH;
    int nvalid = min(BNODES, NN - node0);
    int e0 = boffB[b], e1 = boffB[b + 1];
    if (tid < BNODES) h[tid] = 0;
    __syncthreads();
    for (int e = e0 + tid; e < e1; e += 256)
        atomicAdd(&h[evb[e].x >> 17], 1);
    __syncthreads();
    int v = (tid < BNODES) ? h[tid] : 0;   // my count (dl = tid)
    // inclusive Hillis-Steele over 128 entries
    for (int d = 1; d < BNODES; d <<= 1) {
        int u = (tid >= d && tid < BNODES) ? h[tid - d] : 0;
        __syncthreads();
        if (tid < BNODES) h[tid] += u;
        __syncthreads();
    }
    if (tid < BNODES) {
        int start = e0 + h[tid] - v;       // exclusive
        cur[tid] = start;
        if (tid < nvalid) offs[node0 + tid] = start;
    }
    if (b == NB - 1 && tid == 0) offs[NN] = NE;
    __syncthreads();
    for (int e = e0 + tid; e < e1; e += 256) {
        int2 rec = evb[e];
        int dl = rec.x >> 17;
        int p = atomicAdd(&cur[dl], 1);
        ev[p] = make_int2(rec.x & 0x1FFFF, rec.y);   // random only within 16 KB window
    }
}

// ------- layer A: quarter-wave gather (+x) -> Linear1 (W1 in LDS) -> BN stats -------
__global__ __launch_bounds__(256, 8) void k_layerA(const ushort* __restrict__ xb,
                                                   const int* __restrict__ offs,
                                                   const int2* __restrict__ ev,
                                                   const float* __restrict__ W1,
                                                   const float* __restrict__ b1,
                                                   ushort* __restrict__ hout,
                                                   float* __restrict__ stats) {
    __shared__ float w1[HID * HID];        // 16 KB
    __shared__ float4 rowv[4][16];         // per-wave row buffer, 1 KB
    __shared__ float red[8][HID];          // 2 KB
    int tid = threadIdx.x;
    int wv = tid >> 6, lane = tid & 63;
    int g = lane >> 4, li = lane & 15, c = lane;
    for (int i = tid; i < HID * HID; i += 256) w1[i] = W1[i];
    float bl = b1[c];
    float s1 = 0.f, s2 = 0.f;
    __syncthreads();
    int wave = blockIdx.x * 4 + wv, nw = gridDim.x * 4;
    for (int node = wave; node < NN; node += nw) {
        // gather: each 16-lane group owns one edge, ushort4 (4 ch) per lane
        ushort4 s4 = *(const ushort4*)(xb + (size_t)node * HID + li * 4);
        float4 acc;
        acc.x = (g == 0) ? bf2f(s4.x) : 0.f;
        acc.y = (g == 0) ? bf2f(s4.y) : 0.f;
        acc.z = (g == 0) ? bf2f(s4.z) : 0.f;
        acc.w = (g == 0) ? bf2f(s4.w) : 0.f;
        int e0 = offs[node], e1 = offs[node + 1];
        for (int e = e0; e < e1; e += 8) {      // 8 edges per wave-iter
            int ea = e + g, eb = e + 4 + g;
            int2 ta = ev[(ea < e1) ? ea : (e1 - 1)];
            int2 tb = ev[(eb < e1) ? eb : (e1 - 1)];
            float aa = (ea < e1) ? __int_as_float(ta.y) : 0.f;
            float ab = (eb < e1) ? __int_as_float(tb.y) : 0.f;
            ushort4 ra = *(const ushort4*)(xb + (size_t)ta.x * HID + li * 4);
            ushort4 rb = *(const ushort4*)(xb + (size_t)tb.x * HID + li * 4);
            acc.x += bf2f(ra.x) * aa + bf2f(rb.x) * ab;
            acc.y += bf2f(ra.y) * aa + bf2f(rb.y) * ab;
            acc.z += bf2f(ra.z) * aa + bf2f(rb.z) * ab;
            acc.w += bf2f(ra.w) * aa + bf2f(rb.w) * ab;
        }
        acc.x += __shfl_xor(acc.x, 16, 64); acc.x += __shfl_xor(acc.x, 32, 64);
        acc.y += __shfl_xor(acc.y, 16, 64); acc.y += __shfl_xor(acc.y, 32, 64);
        acc.z += __shfl_xor(acc.z, 16, 64); acc.z += __shfl_xor(acc.z, 32, 64);
        acc.w += __shfl_xor(acc.w, 16, 64); acc.w += __shfl_xor(acc.w, 32, 64);
        if (g == 0) rowv[wv][li] = acc;         // wave-local; lgkmcnt orders RAW
        // Linear1 from LDS: W stride-1 across lanes (conflict-free), row broadcast
        float o = bl;
#pragma unroll
        for (int k4 = 0; k4 < 16; ++k4) {
            float4 rv = rowv[wv][k4];
            o += rv.x * w1[(4 * k4 + 0) * HID + c] + rv.y * w1[(4 * k4 + 1) * HID + c]
               + rv.z * w1[(4 * k4 + 2) * HID + c] + rv.w * w1[(4 * k4 + 3) * HID + c];
        }
        hout[(size_t)node * HID + c] = f2bf(o);
        s1 += o;
        s2 += o * o;
    }
    red[wv][c] = s1;
    red[4 + wv][c] = s2;
    __syncthreads();
    if (wv == 0) {
        atomicAdd(&stats[c], red[0][c] + red[1][c] + red[2][c] + red[3][c]);
        atomicAdd(&stats[HID + c], red[4][c] + red[5][c] + red[6][c] + red[7][c]);
    }
}

// ------- mlp2: BN -> ReLU -> Linear2 -> ReLU; out bf16 (mid) or f32 (last) -------
__global__ __launch_bounds__(256, 4) void k_mlp2(const float* __restrict__ W2,
                                                 const float* __restrict__ b2,
                                                 const float* __restrict__ gamma,
                                                 const float* __restrict__ beta,
                                                 const float* __restrict__ stats,
                                                 const ushort* __restrict__ h,
                                                 ushort* __restrict__ xb_out,
                                                 float* __restrict__ f_out,
                                                 int write_f32) {
    __shared__ float rowlds[4][HID];
    int tid = threadIdx.x, wv = tid >> 6, c = tid & 63;
    float wr[HID];
    {
        volatile const float* wp = W2;       // volatile: forbid remat -> stays in VGPRs
#pragma unroll
        for (int k = 0; k < HID; ++k) wr[k] = wp[k * HID + c];
    }
    float bl = b2[c];
    float mu = stats[c] * (1.0f / NN);
    float var = fmaxf(stats[HID + c] * (1.0f / NN) - mu * mu, 0.f);
    float aC = gamma[c] * rsqrtf(var + BN_EPS);
    float bC = beta[c] - mu * aC;
    int gw = blockIdx.x * 4 + wv, nw = gridDim.x * 4;
    for (int node = gw; node < NN; node += nw) {
        float v = bf2f(h[(size_t)node * HID + c]);
        v = fmaxf(aC * v + bC, 0.f);
        rowlds[wv][c] = v;                    // wave-local buffer, no barrier
        float o = bl;
        const float4* rp = (const float4*)&rowlds[wv][0];
#pragma unroll
        for (int k4 = 0; k4 < 16; ++k4) {
            float4 rv = rp[k4];
            o += rv.x * wr[4 * k4] + rv.y * wr[4 * k4 + 1]
               + rv.z * wr[4 * k4 + 2] + rv.w * wr[4 * k4 + 3];
        }
        o = fmaxf(o, 0.f);
        if (write_f32) f_out[(size_t)node * HID + c] = o;
        else           xb_out[(size_t)node * HID + c] = f2bf(o);
    }
}

extern "C" void kernel_launch(void* const* d_in, const int* in_sizes, int n_in,
                              void* d_out, int out_size, void* d_ws, size_t ws_size,
                              hipStream_t stream) {
    const float* x_in  = (const float*)d_in[0];
    const int*   ei    = (const int*)d_in[1];
    const float* att   = (const float*)d_in[2];
    const float* W1    = (const float*)d_in[3];
    const float* b1    = (const float*)d_in[4];
    const float* gamma = (const float*)d_in[5];
    const float* beta  = (const float*)d_in[6];
    const float* W2    = (const float*)d_in[7];
    const float* b2    = (const float*)d_in[8];
    float* out = (float*)d_out;

    char* ws = (char*)d_ws;
    size_t off = 0;
    auto alloc = [&](size_t bytes) -> void* {
        void* p = ws + off;
        off += (bytes + 255) & ~(size_t)255;
        return p;
    };
    ushort* xb    = (ushort*)alloc((size_t)NN * HID * 2);
    ushort* hb    = (ushort*)alloc((size_t)NN * HID * 2);
    int*    ghist = (int*)alloc((size_t)NB * 4);
    int*    boffB = (int*)alloc((size_t)(NB + 1) * 4);
    int*    gcur  = (int*)alloc((size_t)NB * 4);
    int*    offs  = (int*)alloc((size_t)(NN + 1) * 4);
    int2*   evb   = (int2*)alloc((size_t)NE * 8);
    int2*   ev    = (int2*)alloc((size_t)NE * 8);
    float*  stats = (float*)alloc(NL * 128 * 4);

    hipMemsetAsync(ghist, 0, (size_t)NB * 4, stream);
    hipMemsetAsync(stats, 0, NL * 128 * 4, stream);

    k_conv<<<(NN * HID / 4 + 255) / 256, 256, 0, stream>>>(x_in, xb);
    k_histB<<<BIN_GRID, 256, 0, stream>>>(ei + NE, ghist);
    k_scanB<<<1, 1024, 0, stream>>>(ghist, boffB, gcur);
    k_binB<<<BIN_GRID, 256, 0, stream>>>(ei, att, gcur, evb);
    k_scatter2<<<NB, 256, 0, stream>>>(evb, boffB, offs, ev);

    for (int l = 0; l < NL; ++l) {
        k_layerA<<<2048, 256, 0, stream>>>(xb, offs, ev,
                                           W1 + (size_t)l * HID * HID, b1 + l * HID,
                                           hb, stats + l * 128);
        k_mlp2<<<1024, 256, 0, stream>>>(W2 + (size_t)l * HID * HID, b2 + l * HID,
                                         gamma + l * HID, beta + l * HID,
                                         stats + l * 128, hb,
                                         xb, out, (l == NL - 1) ? 1 : 0);
    }
}

// Round 8
// 729.634 us; speedup vs baseline: 1.2199x; 1.2199x over previous
//
#include <hip/hip_runtime.h>

#define NN 100000
#define NE 1600000
#define HID 64
#define CH 16                  // channels per chunk
#define NL 3
#define BN_EPS 1e-5f
#define BSH 7
#define BNODES 128
#define NB 782                 // ceil(NN / BNODES)
#define BIN_CHUNK 16384
#define BIN_GRID ((NE + BIN_CHUNK - 1) / BIN_CHUNK)

__device__ __forceinline__ float bf2f(unsigned short u) {
    union { unsigned int i; float f; } v; v.i = ((unsigned int)u) << 16; return v.f;
}
__device__ __forceinline__ unsigned short f2bf(float f) {
    union { float f; unsigned int i; } v; v.f = f;
    unsigned int r = v.i + 0x7FFFu + ((v.i >> 16) & 1u);   // RNE
    return (unsigned short)(r >> 16);
}

// ---------------- input convert x f32 -> bf16 chunk-major ----------------
// xc[q][node][m], q = ch>>4, m = ch&15  (each chunk = 3.2 MB, fits per-XCD L2)
__global__ void k_conv(const float* __restrict__ x, ushort* __restrict__ xc) {
    int i = blockIdx.x * blockDim.x + threadIdx.x;   // over NN*HID/4
    float4 v = ((const float4*)x)[i];
    int node = i >> 4, c4 = (i & 15) * 4;
    int q = c4 >> 4, m = c4 & 15;
    ushort4 o;
    o.x = f2bf(v.x); o.y = f2bf(v.y); o.z = f2bf(v.z); o.w = f2bf(v.w);
    *(ushort4*)(xc + (size_t)q * NN * CH + (size_t)node * CH + m) = o;
}

// ---------------- bucket histogram ----------------
__global__ void k_histB(const int* __restrict__ dst, int* __restrict__ ghist) {
    __shared__ int lh[NB];
    for (int i = threadIdx.x; i < NB; i += blockDim.x) lh[i] = 0;
    __syncthreads();
    int base = blockIdx.x * BIN_CHUNK;
    int end = min(base + BIN_CHUNK, NE);
    for (int e = base + threadIdx.x; e < end; e += blockDim.x)
        atomicAdd(&lh[dst[e] >> BSH], 1);
    __syncthreads();
    for (int i = threadIdx.x; i < NB; i += blockDim.x)
        if (lh[i]) atomicAdd(&ghist[i], lh[i]);
}

// ---------------- bucket scan (one block, NB <= 1024) ----------------
__global__ void k_scanB(const int* __restrict__ ghist, int* __restrict__ boffB,
                        int* __restrict__ gcur) {
    __shared__ int t[1024];
    int tid = threadIdx.x;
    int v = (tid < NB) ? ghist[tid] : 0;
    t[tid] = v;
    __syncthreads();
    for (int d = 1; d < 1024; d <<= 1) {
        int u = (tid >= d) ? t[tid - d] : 0;
        __syncthreads();
        t[tid] += u;
        __syncthreads();
    }
    if (tid < NB) { int ex = t[tid] - v; boffB[tid] = ex; gcur[tid] = ex; }
    if (tid == 0) boffB[NB] = NE;
}

// ---------------- binning: block-local hist -> bulk reserve -> write ----------------
__global__ void k_binB(const int* __restrict__ ei, const float* __restrict__ att,
                       int* __restrict__ gcur, int2* __restrict__ evb) {
    __shared__ int lh[NB];
    for (int i = threadIdx.x; i < NB; i += blockDim.x) lh[i] = 0;
    __syncthreads();
    int base = blockIdx.x * BIN_CHUNK;
    int end = min(base + BIN_CHUNK, NE);
    for (int e = base + threadIdx.x; e < end; e += blockDim.x)
        atomicAdd(&lh[ei[NE + e] >> BSH], 1);
    __syncthreads();
    for (int i = threadIdx.x; i < NB; i += blockDim.x) {
        int c = lh[i];
        lh[i] = c ? atomicAdd(&gcur[i], c) : 0;   // lh becomes running cursor
    }
    __syncthreads();
    for (int e = base + threadIdx.x; e < end; e += blockDim.x) {
        int d = ei[NE + e];
        int b = d >> BSH;
        int p = atomicAdd(&lh[b], 1);
        evb[p] = make_int2(ei[e] | ((d & (BNODES - 1)) << 17), __float_as_int(att[e]));
    }
}

// ------- pass 2: per-bucket exact CSR placement; also writes per-node offs -------
__global__ __launch_bounds__(256) void k_scatter2(const int2* __restrict__ evb,
                                                  const int* __restrict__ boffB,
                                                  int* __restrict__ offs,
                                                  int2* __restrict__ ev) {
    __shared__ int h[BNODES];
    __shared__ int cur[BNODES];
    int tid = threadIdx.x;
    int b = blockIdx.x;
    int node0 = b << BSH;
    int nvalid = min(BNODES, NN - node0);
    int e0 = boffB[b], e1 = boffB[b + 1];
    if (tid < BNODES) h[tid] = 0;
    __syncthreads();
    for (int e = e0 + tid; e < e1; e += 256)
        atomicAdd(&h[evb[e].x >> 17], 1);
    __syncthreads();
    int v = (tid < BNODES) ? h[tid] : 0;
    for (int d = 1; d < BNODES; d <<= 1) {
        int u = (tid >= d && tid < BNODES) ? h[tid - d] : 0;
        __syncthreads();
        if (tid < BNODES) h[tid] += u;
        __syncthreads();
    }
    if (tid < BNODES) {
        int start = e0 + h[tid] - v;
        cur[tid] = start;
        if (tid < nvalid) offs[node0 + tid] = start;
    }
    if (b == NB - 1 && tid == 0) offs[NN] = NE;
    __syncthreads();
    for (int e = e0 + tid; e < e1; e += 256) {
        int2 rec = evb[e];
        int dl = rec.x >> 17;
        int p = atomicAdd(&cur[dl], 1);
        ev[p] = make_int2(rec.x & 0x1FFFF, rec.y);
    }
}

// ------- gather: chunk-sharded; chunk pinned to XCD via blockIdx&7 -------
// each 16-lane group owns one edge; 4 consecutive nodes per sweep; full-line stores
__global__ __launch_bounds__(256, 8) void k_gather(const ushort* __restrict__ xc,
                                                   const int* __restrict__ offs,
                                                   const int2* __restrict__ ev,
                                                   ushort* __restrict__ aggc) {
    int tid = threadIdx.x;
    int wv = tid >> 6, lane = tid & 63;
    int g = lane >> 4, m = lane & 15;
    int q = (blockIdx.x & 7) >> 1;                          // chunk = XCD id / 2
    int wb = ((blockIdx.x >> 3) << 1) | (blockIdx.x & 1);   // 0..511 within chunk
    const ushort* xq = xc + (size_t)q * NN * CH;
    ushort* aq = aggc + (size_t)q * NN * CH;
    int slot = wb * 4 + wv;                                 // 0..2047
    for (int base = slot * 4; base < NN; base += 8192) {
        float self = bf2f(xq[(base + g) * CH + m]);         // 128 B coalesced
        float keep = 0.f;
        for (int j = 0; j < 4; ++j) {
            int node = base + j;
            float acc = (g == j) ? self : 0.f;              // +x (eps=0), counted once
            int e0 = offs[node], e1 = offs[node + 1];
            for (int e = e0; e < e1; e += 8) {
                int ea = e + g, eb = ea + 4;
                int2 ta = ev[(ea < e1) ? ea : (e1 - 1)];
                int2 tb = ev[(eb < e1) ? eb : (e1 - 1)];
                float aa = (ea < e1) ? __int_as_float(ta.y) : 0.f;
                float ab = (eb < e1) ? __int_as_float(tb.y) : 0.f;
                float ra = bf2f(xq[ta.x * CH + m]);         // 32 B per group, L2-hot
                float rb = bf2f(xq[tb.x * CH + m]);
                acc += ra * aa + rb * ab;
            }
            acc += __shfl_xor(acc, 16, 64);                 // reduce 4 groups
            acc += __shfl_xor(acc, 32, 64);
            if (g == j) keep = acc;                         // my slot's node
        }
        aq[(base + g) * CH + m] = f2bf(keep);               // 128 B full-line store
    }
}

// ------- mlp1: h = agg @ W1 + b1 (agg chunk-major), BN stats -------
__global__ __launch_bounds__(256, 4) void k_mlp1(const ushort* __restrict__ aggc,
                                                 const float* __restrict__ W1,
                                                 const float* __restrict__ b1,
                                                 ushort* __restrict__ h,
                                                 float* __restrict__ stats) {
    __shared__ float rowlds[4][HID];
    __shared__ float red[8][HID];
    int tid = threadIdx.x, wv = tid >> 6, c = tid & 63;
    const ushort* ac = aggc + (size_t)(c >> 4) * NN * CH + (c & 15);
    float wr[HID];
    {
        volatile const float* wp = W1;       // pin W column in VGPRs
#pragma unroll
        for (int k = 0; k < HID; ++k) wr[k] = wp[k * HID + c];
    }
    float bl = b1[c];
    float s1 = 0.f, s2 = 0.f;
    int gw = blockIdx.x * 4 + wv, nw = gridDim.x * 4;
    for (int node = gw; node < NN; node += nw) {
        rowlds[wv][c] = bf2f(ac[(size_t)node * CH]);
        float o = bl;
        const float4* rp = (const float4*)&rowlds[wv][0];
#pragma unroll
        for (int k4 = 0; k4 < 16; ++k4) {
            float4 rv = rp[k4];
            o += rv.x * wr[4 * k4] + rv.y * wr[4 * k4 + 1]
               + rv.z * wr[4 * k4 + 2] + rv.w * wr[4 * k4 + 3];
        }
        h[(size_t)node * HID + c] = f2bf(o);
        s1 += o;
        s2 += o * o;
    }
    red[wv][c] = s1;
    red[4 + wv][c] = s2;
    __syncthreads();
    if (wv == 0) {
        atomicAdd(&stats[c], red[0][c] + red[1][c] + red[2][c] + red[3][c]);
        atomicAdd(&stats[HID + c], red[4][c] + red[5][c] + red[6][c] + red[7][c]);
    }
}

// ------- mlp2: BN -> ReLU -> Linear2 -> ReLU; chunk-major bf16 out or f32 out -------
__global__ __launch_bounds__(256, 4) void k_mlp2(const float* __restrict__ W2,
                                                 const float* __restrict__ b2,
                                                 const float* __restrict__ gamma,
                                                 const float* __restrict__ beta,
                                                 const float* __restrict__ stats,
                                                 const ushort* __restrict__ h,
                                                 ushort* __restrict__ xc_out,
                                                 float* __restrict__ f_out,
                                                 int write_f32) {
    __shared__ float rowlds[4][HID];
    __shared__ ushort stage[4][4 * HID];   // [wave][q*64 + j*16 + m], 4 nodes
    int tid = threadIdx.x, wv = tid >> 6, c = tid & 63;
    float wr[HID];
    {
        volatile const float* wp = W2;
#pragma unroll
        for (int k = 0; k < HID; ++k) wr[k] = wp[k * HID + c];
    }
    float bl = b2[c];
    float mu = stats[c] * (1.0f / NN);
    float var = fmaxf(stats[HID + c] * (1.0f / NN) - mu * mu, 0.f);
    float aC = gamma[c] * rsqrtf(var + BN_EPS);
    float bC = beta[c] - mu * aC;
    int gw = blockIdx.x * 4 + wv, nw = gridDim.x * 4;
    for (int base = gw * 4; base < NN; base += nw * 4) {
#pragma unroll
        for (int j = 0; j < 4; ++j) {
            int node = base + j;
            float v = bf2f(h[(size_t)node * HID + c]);
            v = fmaxf(aC * v + bC, 0.f);
            rowlds[wv][c] = v;                    // wave-local row exchange
            float o = bl;
            const float4* rp = (const float4*)&rowlds[wv][0];
#pragma unroll
            for (int k4 = 0; k4 < 16; ++k4) {
                float4 rv = rp[k4];
                o += rv.x * wr[4 * k4] + rv.y * wr[4 * k4 + 1]
                   + rv.z * wr[4 * k4 + 2] + rv.w * wr[4 * k4 + 3];
            }
            o = fmaxf(o, 0.f);
            if (write_f32) f_out[(size_t)node * HID + c] = o;
            else stage[wv][(c >> 4) * 64 + j * 16 + (c & 15)] = f2bf(o);
        }
        if (!write_f32) {
            // lane l: 4 ushorts covering chunk q=l>>4, contiguous full-line stores
            int lane = tid & 63;
            ushort4 s4 = *(const ushort4*)&stage[wv][lane * 4];
            int q = lane >> 4;
            *(ushort4*)(xc_out + (size_t)q * NN * CH + (size_t)base * CH
                        + (lane & 15) * 4) = s4;
        }
    }
}

extern "C" void kernel_launch(void* const* d_in, const int* in_sizes, int n_in,
                              void* d_out, int out_size, void* d_ws, size_t ws_size,
                              hipStream_t stream) {
    const float* x_in  = (const float*)d_in[0];
    const int*   ei    = (const int*)d_in[1];
    const float* att   = (const float*)d_in[2];
    const float* W1    = (const float*)d_in[3];
    const float* b1    = (const float*)d_in[4];
    const float* gamma = (const float*)d_in[5];
    const float* beta  = (const float*)d_in[6];
    const float* W2    = (const float*)d_in[7];
    const float* b2    = (const float*)d_in[8];
    float* out = (float*)d_out;

    char* ws = (char*)d_ws;
    size_t off = 0;
    auto alloc = [&](size_t bytes) -> void* {
        void* p = ws + off;
        off += (bytes + 255) & ~(size_t)255;
        return p;
    };
    ushort* xc    = (ushort*)alloc((size_t)NN * HID * 2);   // chunk-major x
    ushort* aggc  = (ushort*)alloc((size_t)NN * HID * 2);   // chunk-major agg
    ushort* hb    = (ushort*)alloc((size_t)NN * HID * 2);   // row-major h
    int*    ghist = (int*)alloc((size_t)NB * 4);
    int*    boffB = (int*)alloc((size_t)(NB + 1) * 4);
    int*    gcur  = (int*)alloc((size_t)NB * 4);
    int*    offs  = (int*)alloc((size_t)(NN + 1) * 4);
    int2*   evb   = (int2*)alloc((size_t)NE * 8);
    int2*   ev    = (int2*)alloc((size_t)NE * 8);
    float*  stats = (float*)alloc(NL * 128 * 4);

    hipMemsetAsync(ghist, 0, (size_t)NB * 4, stream);
    hipMemsetAsync(stats, 0, NL * 128 * 4, stream);

    k_conv<<<(NN * HID / 4 + 255) / 256, 256, 0, stream>>>(x_in, xc);
    k_histB<<<BIN_GRID, 256, 0, stream>>>(ei + NE, ghist);
    k_scanB<<<1, 1024, 0, stream>>>(ghist, boffB, gcur);
    k_binB<<<BIN_GRID, 256, 0, stream>>>(ei, att, gcur, evb);
    k_scatter2<<<NB, 256, 0, stream>>>(evb, boffB, offs, ev);

    for (int l = 0; l < NL; ++l) {
        k_gather<<<2048, 256, 0, stream>>>(xc, offs, ev, aggc);
        k_mlp1<<<1024, 256, 0, stream>>>(aggc, W1 + (size_t)l * HID * HID,
                                         b1 + l * HID, hb, stats + l * 128);
        k_mlp2<<<1024, 256, 0, stream>>>(W2 + (size_t)l * HID * HID, b2 + l * HID,
                                         gamma + l * HID, beta + l * HID,
                                         stats + l * 128, hb,
                                         xc, out, (l == NL - 1) ? 1 : 0);
    }
}

// Round 9
// 594.363 us; speedup vs baseline: 1.4975x; 1.2276x over previous
//
#include <hip/hip_runtime.h>

#define NN 100000
#define NE 1600000
#define HID 64
#define CH 16                  // channels per chunk
#define NL 3
#define BN_EPS 1e-5f
#define BSH 7
#define BNODES 128
#define NB 782                 // ceil(NN / BNODES)
#define BIN_CHUNK 16384
#define BIN_GRID ((NE + BIN_CHUNK - 1) / BIN_CHUNK)

__device__ __forceinline__ float bf2f(unsigned short u) {
    union { unsigned int i; float f; } v; v.i = ((unsigned int)u) << 16; return v.f;
}
__device__ __forceinline__ unsigned short f2bf(float f) {
    union { float f; unsigned int i; } v; v.f = f;
    unsigned int r = v.i + 0x7FFFu + ((v.i >> 16) & 1u);   // RNE
    return (unsigned short)(r >> 16);
}

// ---------------- input convert x f32 -> bf16 chunk-major ----------------
// xc[q][node][m], q = ch>>4, m = ch&15  (each chunk = 3.2 MB, fits per-XCD L2)
__global__ void k_conv(const float* __restrict__ x, ushort* __restrict__ xc) {
    int i = blockIdx.x * blockDim.x + threadIdx.x;   // over NN*HID/4
    float4 v = ((const float4*)x)[i];
    int node = i >> 4, c4 = (i & 15) * 4;
    int q = c4 >> 4, m = c4 & 15;
    ushort4 o;
    o.x = f2bf(v.x); o.y = f2bf(v.y); o.z = f2bf(v.z); o.w = f2bf(v.w);
    *(ushort4*)(xc + (size_t)q * NN * CH + (size_t)node * CH + m) = o;
}

// ---------------- bucket histogram ----------------
__global__ void k_histB(const int* __restrict__ dst, int* __restrict__ ghist) {
    __shared__ int lh[NB];
    for (int i = threadIdx.x; i < NB; i += blockDim.x) lh[i] = 0;
    __syncthreads();
    int base = blockIdx.x * BIN_CHUNK;
    int end = min(base + BIN_CHUNK, NE);
    for (int e = base + threadIdx.x; e < end; e += blockDim.x)
        atomicAdd(&lh[dst[e] >> BSH], 1);
    __syncthreads();
    for (int i = threadIdx.x; i < NB; i += blockDim.x)
        if (lh[i]) atomicAdd(&ghist[i], lh[i]);
}

// ---------------- bucket scan (one block, NB <= 1024) ----------------
__global__ void k_scanB(const int* __restrict__ ghist, int* __restrict__ boffB,
                        int* __restrict__ gcur) {
    __shared__ int t[1024];
    int tid = threadIdx.x;
    int v = (tid < NB) ? ghist[tid] : 0;
    t[tid] = v;
    __syncthreads();
    for (int d = 1; d < 1024; d <<= 1) {
        int u = (tid >= d) ? t[tid - d] : 0;
        __syncthreads();
        t[tid] += u;
        __syncthreads();
    }
    if (tid < NB) { int ex = t[tid] - v; boffB[tid] = ex; gcur[tid] = ex; }
    if (tid == 0) boffB[NB] = NE;
}

// ---------------- binning: block-local hist -> bulk reserve -> write ----------------
__global__ void k_binB(const int* __restrict__ ei, const float* __restrict__ att,
                       int* __restrict__ gcur, int2* __restrict__ evb) {
    __shared__ int lh[NB];
    for (int i = threadIdx.x; i < NB; i += blockDim.x) lh[i] = 0;
    __syncthreads();
    int base = blockIdx.x * BIN_CHUNK;
    int end = min(base + BIN_CHUNK, NE);
    for (int e = base + threadIdx.x; e < end; e += blockDim.x)
        atomicAdd(&lh[ei[NE + e] >> BSH], 1);
    __syncthreads();
    for (int i = threadIdx.x; i < NB; i += blockDim.x) {
        int c = lh[i];
        lh[i] = c ? atomicAdd(&gcur[i], c) : 0;   // lh becomes running cursor
    }
    __syncthreads();
    for (int e = base + threadIdx.x; e < end; e += blockDim.x) {
        int d = ei[NE + e];
        int b = d >> BSH;
        int p = atomicAdd(&lh[b], 1);
        evb[p] = make_int2(ei[e] | ((d & (BNODES - 1)) << 17), __float_as_int(att[e]));
    }
}

// ------- pass 2: per-bucket CSR placement; compressed 4 B records -------
__global__ __launch_bounds__(256) void k_scatter2(const int2* __restrict__ evb,
                                                  const int* __restrict__ boffB,
                                                  int* __restrict__ offs,
                                                  uint* __restrict__ evc) {
    __shared__ int h[BNODES];
    __shared__ int cur[BNODES];
    int tid = threadIdx.x;
    int b = blockIdx.x;
    int node0 = b << BSH;
    int nvalid = min(BNODES, NN - node0);
    int e0 = boffB[b], e1 = boffB[b + 1];
    if (tid < BNODES) h[tid] = 0;
    __syncthreads();
    for (int e = e0 + tid; e < e1; e += 256)
        atomicAdd(&h[evb[e].x >> 17], 1);
    __syncthreads();
    int v = (tid < BNODES) ? h[tid] : 0;
    for (int d = 1; d < BNODES; d <<= 1) {
        int u = (tid >= d && tid < BNODES) ? h[tid - d] : 0;
        __syncthreads();
        if (tid < BNODES) h[tid] += u;
        __syncthreads();
    }
    if (tid < BNODES) {
        int start = e0 + h[tid] - v;
        cur[tid] = start;
        if (tid < nvalid) offs[node0 + tid] = start;
    }
    if (b == NB - 1 && tid == 0) offs[NN] = NE;
    __syncthreads();
    for (int e = e0 + tid; e < e1; e += 256) {
        int2 rec = evb[e];
        int dl = rec.x >> 17;
        int p = atomicAdd(&cur[dl], 1);
        uint a15 = (uint)(__int_as_float(rec.y) * 32767.0f + 0.5f);
        evc[p] = ((uint)rec.x & 0x1FFFFu) | (a15 << 17);   // src | att15
    }
}

// ------- gather: chunk-sharded, 8 slots x 2ch, node-ahead ev prefetch -------
__global__ __launch_bounds__(256, 8) void k_gather(const ushort* __restrict__ xc,
                                                   const int* __restrict__ offs,
                                                   const uint* __restrict__ evc,
                                                   ushort* __restrict__ aggc) {
    int tid = threadIdx.x;
    int wv = tid >> 6, lane = tid & 63;
    int g = lane >> 3;             // edge slot 0..7
    int c2 = lane & 7;             // channel pair (ch = 2*c2, 2*c2+1)
    int q = (blockIdx.x & 7) >> 1;                          // chunk pinned to XCD pair
    int wb = ((blockIdx.x >> 3) << 1) | (blockIdx.x & 1);   // 0..511 within chunk
    const ushort* xq = xc + (size_t)q * NN * CH + c2 * 2;
    ushort* aq = aggc + (size_t)q * NN * CH;
    int slot = wb * 4 + wv;        // 0..2047
    for (int base = slot * 8; base < NN; base += 2048 * 8) {
        uint selfraw = *(const uint*)(xq + (base + g) * CH);      // 256 B coalesced
        int myoff0 = offs[base + c2];
        int myoff1 = offs[base + c2 + 1];
        float rx = 0.f, ry = 0.f;
        int e0n = __shfl(myoff0, 0, 64);
        int e1n = __shfl(myoff1, 0, 64);
        uint evj = evc[min(e0n + g, max(e1n - 1, 0))];            // prefetch j=0
        for (int j = 0; j < 8; ++j) {
            int e0 = e0n, e1 = e1n;
            uint evu = evj;
            if (j < 7) {                                          // prefetch j+1
                e0n = __shfl(myoff0, j + 1, 64);
                e1n = __shfl(myoff1, j + 1, 64);
                evj = evc[min(e0n + g, max(e1n - 1, 0))];
            }
            int e1m1 = max(e1 - 1, 0);
            float ax = 0.f, ay = 0.f;
            for (int e = e0; e < e1; e += 8) {
                uint evn = evc[min(e + 8 + g, e1m1)];             // next-line prefetch
                float a = (e + g < e1) ? (float)(evu >> 17) * (1.0f / 32767.0f) : 0.f;
                int src = evu & 0x1FFFF;
                uint r = *(const uint*)(xq + src * CH);
                union { uint u; float f; } lo, hi;
                lo.u = r << 16; hi.u = r & 0xFFFF0000u;
                ax += lo.f * a; ay += hi.f * a;
                evu = evn;
            }
            ax += __shfl_xor(ax, 8, 64);  ay += __shfl_xor(ay, 8, 64);
            ax += __shfl_xor(ax, 16, 64); ay += __shfl_xor(ay, 16, 64);
            ax += __shfl_xor(ax, 32, 64); ay += __shfl_xor(ay, 32, 64);
            if (g == j) { rx = ax; ry = ay; }
        }
        union { uint u; float f; } sl, sh;
        sl.u = selfraw << 16; sh.u = selfraw & 0xFFFF0000u;
        rx += sl.f; ry += sh.f;                                   // +x (eps=0)
        uint outp = ((uint)f2bf(rx)) | (((uint)f2bf(ry)) << 16);
        *(uint*)(aq + (base + g) * CH + c2 * 2) = outp;           // 256 B store
    }
}

// ------- mlp1: h = agg @ W1 + b1 (agg chunk-major), BN stats -------
__global__ __launch_bounds__(256, 4) void k_mlp1(const ushort* __restrict__ aggc,
                                                 const float* __restrict__ W1,
                                                 const float* __restrict__ b1,
                                                 ushort* __restrict__ h,
                                                 float* __restrict__ stats) {
    __shared__ float rowlds[4][HID];
    __shared__ float red[8][HID];
    int tid = threadIdx.x, wv = tid >> 6, c = tid & 63;
    const ushort* ac = aggc + (size_t)(c >> 4) * NN * CH + (c & 15);
    float wr[HID];
    {
        volatile const float* wp = W1;       // pin W column in VGPRs
#pragma unroll
        for (int k = 0; k < HID; ++k) wr[k] = wp[k * HID + c];
    }
    float bl = b1[c];
    float s1 = 0.f, s2 = 0.f;
    int gw = blockIdx.x * 4 + wv, nw = gridDim.x * 4;
    for (int node = gw; node < NN; node += nw) {
        rowlds[wv][c] = bf2f(ac[(size_t)node * CH]);
        float o = bl;
        const float4* rp = (const float4*)&rowlds[wv][0];
#pragma unroll
        for (int k4 = 0; k4 < 16; ++k4) {
            float4 rv = rp[k4];
            o += rv.x * wr[4 * k4] + rv.y * wr[4 * k4 + 1]
               + rv.z * wr[4 * k4 + 2] + rv.w * wr[4 * k4 + 3];
        }
        h[(size_t)node * HID + c] = f2bf(o);
        s1 += o;
        s2 += o * o;
    }
    red[wv][c] = s1;
    red[4 + wv][c] = s2;
    __syncthreads();
    if (wv == 0) {
        atomicAdd(&stats[c], red[0][c] + red[1][c] + red[2][c] + red[3][c]);
        atomicAdd(&stats[HID + c], red[4][c] + red[5][c] + red[6][c] + red[7][c]);
    }
}

// ------- mlp2: BN -> ReLU -> Linear2 -> ReLU; chunk-major bf16 out or f32 out -------
__global__ __launch_bounds__(256, 4) void k_mlp2(const float* __restrict__ W2,
                                                 const float* __restrict__ b2,
                                                 const float* __restrict__ gamma,
                                                 const float* __restrict__ beta,
                                                 const float* __restrict__ stats,
                                                 const ushort* __restrict__ h,
                                                 ushort* __restrict__ xc_out,
                                                 float* __restrict__ f_out,
                                                 int write_f32) {
    __shared__ float rowlds[4][HID];
    __shared__ ushort stage[4][4 * HID];   // [wave][q*64 + j*16 + m], 4 nodes
    int tid = threadIdx.x, wv = tid >> 6, c = tid & 63;
    float wr[HID];
    {
        volatile const float* wp = W2;
#pragma unroll
        for (int k = 0; k < HID; ++k) wr[k] = wp[k * HID + c];
    }
    float bl = b2[c];
    float mu = stats[c] * (1.0f / NN);
    float var = fmaxf(stats[HID + c] * (1.0f / NN) - mu * mu, 0.f);
    float aC = gamma[c] * rsqrtf(var + BN_EPS);
    float bC = beta[c] - mu * aC;
    int gw = blockIdx.x * 4 + wv, nw = gridDim.x * 4;
    for (int base = gw * 4; base < NN; base += nw * 4) {
#pragma unroll
        for (int j = 0; j < 4; ++j) {
            int node = base + j;
            float v = bf2f(h[(size_t)node * HID + c]);
            v = fmaxf(aC * v + bC, 0.f);
            rowlds[wv][c] = v;                    // wave-local row exchange
            float o = bl;
            const float4* rp = (const float4*)&rowlds[wv][0];
#pragma unroll
            for (int k4 = 0; k4 < 16; ++k4) {
                float4 rv = rp[k4];
                o += rv.x * wr[4 * k4] + rv.y * wr[4 * k4 + 1]
                   + rv.z * wr[4 * k4 + 2] + rv.w * wr[4 * k4 + 3];
            }
            o = fmaxf(o, 0.f);
            if (write_f32) f_out[(size_t)node * HID + c] = o;
            else stage[wv][(c >> 4) * 64 + j * 16 + (c & 15)] = f2bf(o);
        }
        if (!write_f32) {
            int lane = tid & 63;
            ushort4 s4 = *(const ushort4*)&stage[wv][lane * 4];
            int q = lane >> 4;
            *(ushort4*)(xc_out + (size_t)q * NN * CH + (size_t)base * CH
                        + (lane & 15) * 4) = s4;
        }
    }
}

extern "C" void kernel_launch(void* const* d_in, const int* in_sizes, int n_in,
                              void* d_out, int out_size, void* d_ws, size_t ws_size,
                              hipStream_t stream) {
    const float* x_in  = (const float*)d_in[0];
    const int*   ei    = (const int*)d_in[1];
    const float* att   = (const float*)d_in[2];
    const float* W1    = (const float*)d_in[3];
    const float* b1    = (const float*)d_in[4];
    const float* gamma = (const float*)d_in[5];
    const float* beta  = (const float*)d_in[6];
    const float* W2    = (const float*)d_in[7];
    const float* b2    = (const float*)d_in[8];
    float* out = (float*)d_out;

    char* ws = (char*)d_ws;
    size_t off = 0;
    auto alloc = [&](size_t bytes) -> void* {
        void* p = ws + off;
        off += (bytes + 255) & ~(size_t)255;
        return p;
    };
    ushort* xc    = (ushort*)alloc((size_t)NN * HID * 2);   // chunk-major x
    ushort* aggc  = (ushort*)alloc((size_t)NN * HID * 2);   // chunk-major agg
    ushort* hb    = (ushort*)alloc((size_t)NN * HID * 2);   // row-major h
    int*    ghist = (int*)alloc((size_t)NB * 4);
    int*    boffB = (int*)alloc((size_t)(NB + 1) * 4);
    int*    gcur  = (int*)alloc((size_t)NB * 4);
    int*    offs  = (int*)alloc((size_t)(NN + 1) * 4);
    int2*   evb   = (int2*)alloc((size_t)NE * 8);
    uint*   evc   = (uint*)alloc((size_t)NE * 4);           // compressed records
    float*  stats = (float*)alloc(NL * 128 * 4);

    hipMemsetAsync(ghist, 0, (size_t)NB * 4, stream);
    hipMemsetAsync(stats, 0, NL * 128 * 4, stream);

    k_conv<<<(NN * HID / 4 + 255) / 256, 256, 0, stream>>>(x_in, xc);
    k_histB<<<BIN_GRID, 256, 0, stream>>>(ei + NE, ghist);
    k_scanB<<<1, 1024, 0, stream>>>(ghist, boffB, gcur);
    k_binB<<<BIN_GRID, 256, 0, stream>>>(ei, att, gcur, evb);
    k_scatter2<<<NB, 256, 0, stream>>>(evb, boffB, offs, evc);

    for (int l = 0; l < NL; ++l) {
        k_gather<<<2048, 256, 0, stream>>>(xc, offs, evc, aggc);
        k_mlp1<<<1024, 256, 0, stream>>>(aggc, W1 + (size_t)l * HID * HID,
                                         b1 + l * HID, hb, stats + l * 128);
        k_mlp2<<<1024, 256, 0, stream>>>(W2 + (size_t)l * HID * HID, b2 + l * HID,
                                         gamma + l * HID, beta + l * HID,
                                         stats + l * 128, hb,
                                         xc, out, (l == NL - 1) ? 1 : 0);
    }
}

// Round 10
// 550.668 us; speedup vs baseline: 1.6163x; 1.0793x over previous
//
#include <hip/hip_runtime.h>

#define NN 100000
#define NE 1600000
#define HID 64
#define CH 16                  // channels per chunk
#define NL 3
#define BN_EPS 1e-5f
#define BSH 7
#define BNODES 128
#define NB 782                 // ceil(NN / BNODES)
#define GP 16                  // global counter pad (ints) -> 64 B/line
#define BIN_CHUNK 8192
#define BIN_GRID ((NE + BIN_CHUNK - 1) / BIN_CHUNK)

__device__ __forceinline__ float bf2f(unsigned short u) {
    union { unsigned int i; float f; } v; v.i = ((unsigned int)u) << 16; return v.f;
}
__device__ __forceinline__ unsigned short f2bf(float f) {
    union { float f; unsigned int i; } v; v.f = f;
    unsigned int r = v.i + 0x7FFFu + ((v.i >> 16) & 1u);   // RNE
    return (unsigned short)(r >> 16);
}

// ---------------- input convert x f32 -> bf16 chunk-major ----------------
__global__ void k_conv(const float* __restrict__ x, ushort* __restrict__ xc) {
    int i = blockIdx.x * blockDim.x + threadIdx.x;   // over NN*HID/4
    float4 v = ((const float4*)x)[i];
    int node = i >> 4, c4 = (i & 15) * 4;
    int q = c4 >> 4, m = c4 & 15;
    ushort4 o;
    o.x = f2bf(v.x); o.y = f2bf(v.y); o.z = f2bf(v.z); o.w = f2bf(v.w);
    *(ushort4*)(xc + (size_t)q * NN * CH + (size_t)node * CH + m) = o;
}

// ---------------- bucket histogram: 1024 thr, int4 batch ----------------
__global__ __launch_bounds__(1024) void k_histB(const int* __restrict__ dst,
                                                int* __restrict__ ghist) {
    __shared__ int lh[NB];
    int tid = threadIdx.x;
    for (int i = tid; i < NB; i += 1024) lh[i] = 0;
    __syncthreads();
    int base = blockIdx.x * BIN_CHUNK;
    int end = min(base + BIN_CHUNK, NE);
    for (int e = base + tid * 4; e + 3 < end; e += 4096) {
        int4 d = *(const int4*)(dst + e);
        atomicAdd(&lh[d.x >> BSH], 1);
        atomicAdd(&lh[d.y >> BSH], 1);
        atomicAdd(&lh[d.z >> BSH], 1);
        atomicAdd(&lh[d.w >> BSH], 1);
    }
    __syncthreads();
    for (int i = tid; i < NB; i += 1024)
        if (lh[i]) atomicAdd(&ghist[i * GP], lh[i]);
}

// ---------------- bucket scan (one block, NB <= 1024) ----------------
__global__ void k_scanB(const int* __restrict__ ghist, int* __restrict__ boffB,
                        int* __restrict__ gcur) {
    __shared__ int t[1024];
    int tid = threadIdx.x;
    int v = (tid < NB) ? ghist[tid * GP] : 0;
    t[tid] = v;
    __syncthreads();
    for (int d = 1; d < 1024; d <<= 1) {
        int u = (tid >= d) ? t[tid - d] : 0;
        __syncthreads();
        t[tid] += u;
        __syncthreads();
    }
    if (tid < NB) { int ex = t[tid] - v; boffB[tid] = ex; gcur[tid * GP] = ex; }
    if (tid == 0) boffB[NB] = NE;
}

// ---------------- binning: 1024 thr, 4-edge batch, padded reserve ----------------
__global__ __launch_bounds__(1024) void k_binB(const int* __restrict__ ei,
                                               const float* __restrict__ att,
                                               int* __restrict__ gcur,
                                               int2* __restrict__ evb) {
    __shared__ int lh[NB];
    int tid = threadIdx.x;
    for (int i = tid; i < NB; i += 1024) lh[i] = 0;
    __syncthreads();
    int base = blockIdx.x * BIN_CHUNK;
    int end = min(base + BIN_CHUNK, NE);
    for (int e = base + tid * 4; e + 3 < end; e += 4096) {
        int4 d = *(const int4*)(ei + NE + e);
        atomicAdd(&lh[d.x >> BSH], 1);
        atomicAdd(&lh[d.y >> BSH], 1);
        atomicAdd(&lh[d.z >> BSH], 1);
        atomicAdd(&lh[d.w >> BSH], 1);
    }
    __syncthreads();
    for (int i = tid; i < NB; i += 1024) {
        int c = lh[i];
        lh[i] = c ? atomicAdd(&gcur[i * GP], c) : 0;   // lh becomes running cursor
    }
    __syncthreads();
    for (int e = base + tid * 4; e + 3 < end; e += 4096) {
        int4 s = *(const int4*)(ei + e);
        int4 d = *(const int4*)(ei + NE + e);
        float4 a = *(const float4*)(att + e);
        int p0 = atomicAdd(&lh[d.x >> BSH], 1);
        int p1 = atomicAdd(&lh[d.y >> BSH], 1);
        int p2 = atomicAdd(&lh[d.z >> BSH], 1);
        int p3 = atomicAdd(&lh[d.w >> BSH], 1);
        evb[p0] = make_int2(s.x | ((d.x & (BNODES - 1)) << 17), __float_as_int(a.x));
        evb[p1] = make_int2(s.y | ((d.y & (BNODES - 1)) << 17), __float_as_int(a.y));
        evb[p2] = make_int2(s.z | ((d.z & (BNODES - 1)) << 17), __float_as_int(a.z));
        evb[p3] = make_int2(s.w | ((d.w & (BNODES - 1)) << 17), __float_as_int(a.w));
    }
}

// ------- pass 2: per-bucket CSR placement; compressed 4 B records -------
__global__ __launch_bounds__(256) void k_scatter2(const int2* __restrict__ evb,
                                                  const int* __restrict__ boffB,
                                                  int* __restrict__ offs,
                                                  uint* __restrict__ evc) {
    __shared__ int h[BNODES];
    __shared__ int cur[BNODES];
    int tid = threadIdx.x;
    int b = blockIdx.x;
    int node0 = b << BSH;
    int nvalid = min(BNODES, NN - node0);
    int e0 = boffB[b], e1 = boffB[b + 1];
    if (tid < BNODES) h[tid] = 0;
    __syncthreads();
    for (int e = e0 + tid * 2; e < e1; e += 512) {
        int2 r0 = evb[e];
        int v1 = (e + 1 < e1);
        int2 r1 = evb[v1 ? e + 1 : e];
        atomicAdd(&h[r0.x >> 17], 1);
        if (v1) atomicAdd(&h[r1.x >> 17], 1);
    }
    __syncthreads();
    int v = (tid < BNODES) ? h[tid] : 0;
    for (int d = 1; d < BNODES; d <<= 1) {
        int u = (tid >= d && tid < BNODES) ? h[tid - d] : 0;
        __syncthreads();
        if (tid < BNODES) h[tid] += u;
        __syncthreads();
    }
    if (tid < BNODES) {
        int start = e0 + h[tid] - v;
        cur[tid] = start;
        if (tid < nvalid) offs[node0 + tid] = start;
    }
    if (b == NB - 1 && tid == 0) offs[NN] = NE;
    __syncthreads();
    for (int e = e0 + tid * 2; e < e1; e += 512) {
        int2 r0 = evb[e];
        int v1 = (e + 1 < e1);
        int2 r1 = evb[v1 ? e + 1 : e];
        int p0 = atomicAdd(&cur[r0.x >> 17], 1);
        int p1 = v1 ? atomicAdd(&cur[r1.x >> 17], 1) : 0;
        uint a0 = (uint)(__int_as_float(r0.y) * 32767.0f + 0.5f);
        evc[p0] = ((uint)r0.x & 0x1FFFFu) | (a0 << 17);
        if (v1) {
            uint a1 = (uint)(__int_as_float(r1.y) * 32767.0f + 0.5f);
            evc[p1] = ((uint)r1.x & 0x1FFFFu) | (a1 << 17);
        }
    }
}

// ------- gather: chunk-sharded, 8 slots x 2ch, node-ahead ev prefetch -------
__global__ __launch_bounds__(256, 8) void k_gather(const ushort* __restrict__ xc,
                                                   const int* __restrict__ offs,
                                                   const uint* __restrict__ evc,
                                                   ushort* __restrict__ aggc) {
    int tid = threadIdx.x;
    int wv = tid >> 6, lane = tid & 63;
    int g = lane >> 3;             // edge slot 0..7
    int c2 = lane & 7;             // channel pair (ch = 2*c2, 2*c2+1)
    int q = (blockIdx.x & 7) >> 1;                          // chunk pinned to XCD pair
    int wb = ((blockIdx.x >> 3) << 1) | (blockIdx.x & 1);   // 0..511 within chunk
    const ushort* xq = xc + (size_t)q * NN * CH + c2 * 2;
    ushort* aq = aggc + (size_t)q * NN * CH;
    int slot = wb * 4 + wv;        // 0..2047
    for (int base = slot * 8; base < NN; base += 2048 * 8) {
        uint selfraw = *(const uint*)(xq + (base + g) * CH);      // 256 B coalesced
        int myoff0 = offs[base + c2];
        int myoff1 = offs[base + c2 + 1];
        float rx = 0.f, ry = 0.f;
        int e0n = __shfl(myoff0, 0, 64);
        int e1n = __shfl(myoff1, 0, 64);
        uint evj = evc[min(e0n + g, max(e1n - 1, 0))];            // prefetch j=0
        for (int j = 0; j < 8; ++j) {
            int e0 = e0n, e1 = e1n;
            uint evu = evj;
            if (j < 7) {                                          // prefetch j+1
                e0n = __shfl(myoff0, j + 1, 64);
                e1n = __shfl(myoff1, j + 1, 64);
                evj = evc[min(e0n + g, max(e1n - 1, 0))];
            }
            int e1m1 = max(e1 - 1, 0);
            float ax = 0.f, ay = 0.f;
            for (int e = e0; e < e1; e += 8) {
                uint evn = evc[min(e + 8 + g, e1m1)];             // next-line prefetch
                float a = (e + g < e1) ? (float)(evu >> 17) * (1.0f / 32767.0f) : 0.f;
                int src = evu & 0x1FFFF;
                uint r = *(const uint*)(xq + src * CH);
                union { uint u; float f; } lo, hi;
                lo.u = r << 16; hi.u = r & 0xFFFF0000u;
                ax += lo.f * a; ay += hi.f * a;
                evu = evn;
            }
            ax += __shfl_xor(ax, 8, 64);  ay += __shfl_xor(ay, 8, 64);
            ax += __shfl_xor(ax, 16, 64); ay += __shfl_xor(ay, 16, 64);
            ax += __shfl_xor(ax, 32, 64); ay += __shfl_xor(ay, 32, 64);
            if (g == j) { rx = ax; ry = ay; }
        }
        union { uint u; float f; } sl, sh;
        sl.u = selfraw << 16; sh.u = selfraw & 0xFFFF0000u;
        rx += sl.f; ry += sh.f;                                   // +x (eps=0)
        uint outp = ((uint)f2bf(rx)) | (((uint)f2bf(ry)) << 16);
        *(uint*)(aq + (base + g) * CH + c2 * 2) = outp;           // 256 B store
    }
}

// ------- mlp1: h = agg @ W1 + b1 (agg chunk-major), BN stats -------
__global__ __launch_bounds__(256, 4) void k_mlp1(const ushort* __restrict__ aggc,
                                                 const float* __restrict__ W1,
                                                 const float* __restrict__ b1,
                                                 ushort* __restrict__ h,
                                                 float* __restrict__ stats) {
    __shared__ float rowlds[4][HID];
    __shared__ float red[8][HID];
    int tid = threadIdx.x, wv = tid >> 6, c = tid & 63;
    const ushort* ac = aggc + (size_t)(c >> 4) * NN * CH + (c & 15);
    float wr[HID];
    {
        volatile const float* wp = W1;       // pin W column in VGPRs
#pragma unroll
        for (int k = 0; k < HID; ++k) wr[k] = wp[k * HID + c];
    }
    float bl = b1[c];
    float s1 = 0.f, s2 = 0.f;
    int gw = blockIdx.x * 4 + wv, nw = gridDim.x * 4;
    for (int node = gw; node < NN; node += nw) {
        rowlds[wv][c] = bf2f(ac[(size_t)node * CH]);
        float o = bl;
        const float4* rp = (const float4*)&rowlds[wv][0];
#pragma unroll
        for (int k4 = 0; k4 < 16; ++k4) {
            float4 rv = rp[k4];
            o += rv.x * wr[4 * k4] + rv.y * wr[4 * k4 + 1]
               + rv.z * wr[4 * k4 + 2] + rv.w * wr[4 * k4 + 3];
        }
        h[(size_t)node * HID + c] = f2bf(o);
        s1 += o;
        s2 += o * o;
    }
    red[wv][c] = s1;
    red[4 + wv][c] = s2;
    __syncthreads();
    if (wv == 0) {
        atomicAdd(&stats[c], red[0][c] + red[1][c] + red[2][c] + red[3][c]);
        atomicAdd(&stats[HID + c], red[4][c] + red[5][c] + red[6][c] + red[7][c]);
    }
}

// ------- mlp2: BN -> ReLU -> Linear2 -> ReLU; chunk-major bf16 out or f32 out -------
__global__ __launch_bounds__(256, 4) void k_mlp2(const float* __restrict__ W2,
                                                 const float* __restrict__ b2,
                                                 const float* __restrict__ gamma,
                                                 const float* __restrict__ beta,
                                                 const float* __restrict__ stats,
                                                 const ushort* __restrict__ h,
                                                 ushort* __restrict__ xc_out,
                                                 float* __restrict__ f_out,
                                                 int write_f32) {
    __shared__ float rowlds[4][HID];
    __shared__ ushort stage[4][4 * HID];   // [wave][q*64 + j*16 + m], 4 nodes
    int tid = threadIdx.x, wv = tid >> 6, c = tid & 63;
    float wr[HID];
    {
        volatile const float* wp = W2;
#pragma unroll
        for (int k = 0; k < HID; ++k) wr[k] = wp[k * HID + c];
    }
    float bl = b2[c];
    float mu = stats[c] * (1.0f / NN);
    float var = fmaxf(stats[HID + c] * (1.0f / NN) - mu * mu, 0.f);
    float aC = gamma[c] * rsqrtf(var + BN_EPS);
    float bC = beta[c] - mu * aC;
    int gw = blockIdx.x * 4 + wv, nw = gridDim.x * 4;
    for (int base = gw * 4; base < NN; base += nw * 4) {
#pragma unroll
        for (int j = 0; j < 4; ++j) {
            int node = base + j;
            float v = bf2f(h[(size_t)node * HID + c]);
            v = fmaxf(aC * v + bC, 0.f);
            rowlds[wv][c] = v;                    // wave-local row exchange
            float o = bl;
            const float4* rp = (const float4*)&rowlds[wv][0];
#pragma unroll
            for (int k4 = 0; k4 < 16; ++k4) {
                float4 rv = rp[k4];
                o += rv.x * wr[4 * k4] + rv.y * wr[4 * k4 + 1]
                   + rv.z * wr[4 * k4 + 2] + rv.w * wr[4 * k4 + 3];
            }
            o = fmaxf(o, 0.f);
            if (write_f32) f_out[(size_t)node * HID + c] = o;
            else stage[wv][(c >> 4) * 64 + j * 16 + (c & 15)] = f2bf(o);
        }
        if (!write_f32) {
            int lane = tid & 63;
            ushort4 s4 = *(const ushort4*)&stage[wv][lane * 4];
            int q = lane >> 4;
            *(ushort4*)(xc_out + (size_t)q * NN * CH + (size_t)base * CH
                        + (lane & 15) * 4) = s4;
        }
    }
}

extern "C" void kernel_launch(void* const* d_in, const int* in_sizes, int n_in,
                              void* d_out, int out_size, void* d_ws, size_t ws_size,
                              hipStream_t stream) {
    const float* x_in  = (const float*)d_in[0];
    const int*   ei    = (const int*)d_in[1];
    const float* att   = (const float*)d_in[2];
    const float* W1    = (const float*)d_in[3];
    const float* b1    = (const float*)d_in[4];
    const float* gamma = (const float*)d_in[5];
    const float* beta  = (const float*)d_in[6];
    const float* W2    = (const float*)d_in[7];
    const float* b2    = (const float*)d_in[8];
    float* out = (float*)d_out;

    char* ws = (char*)d_ws;
    size_t off = 0;
    auto alloc = [&](size_t bytes) -> void* {
        void* p = ws + off;
        off += (bytes + 255) & ~(size_t)255;
        return p;
    };
    ushort* xc    = (ushort*)alloc((size_t)NN * HID * 2);   // chunk-major x
    ushort* aggc  = (ushort*)alloc((size_t)NN * HID * 2);   // chunk-major agg
    ushort* hb    = (ushort*)alloc((size_t)NN * HID * 2);   // row-major h
    int*    ghist = (int*)alloc((size_t)NB * GP * 4);
    int*    boffB = (int*)alloc((size_t)(NB + 1) * 4);
    int*    gcur  = (int*)alloc((size_t)NB * GP * 4);
    int*    offs  = (int*)alloc((size_t)(NN + 1) * 4);
    int2*   evb   = (int2*)alloc((size_t)NE * 8);
    uint*   evc   = (uint*)alloc((size_t)NE * 4);           // compressed records
    float*  stats = (float*)alloc(NL * 128 * 4);

    hipMemsetAsync(ghist, 0, (size_t)NB * GP * 4, stream);
    hipMemsetAsync(stats, 0, NL * 128 * 4, stream);

    k_conv<<<(NN * HID / 4 + 255) / 256, 256, 0, stream>>>(x_in, xc);
    k_histB<<<BIN_GRID, 1024, 0, stream>>>(ei + NE, ghist);
    k_scanB<<<1, 1024, 0, stream>>>(ghist, boffB, gcur);
    k_binB<<<BIN_GRID, 1024, 0, stream>>>(ei, att, gcur, evb);
    k_scatter2<<<NB, 256, 0, stream>>>(evb, boffB, offs, evc);

    for (int l = 0; l < NL; ++l) {
        k_gather<<<2048, 256, 0, stream>>>(xc, offs, evc, aggc);
        k_mlp1<<<1024, 256, 0, stream>>>(aggc, W1 + (size_t)l * HID * HID,
                                         b1 + l * HID, hb, stats + l * 128);
        k_mlp2<<<1024, 256, 0, stream>>>(W2 + (size_t)l * HID * HID, b2 + l * HID,
                                         gamma + l * HID, beta + l * HID,
                                         stats + l * 128, hb,
                                         xc, out, (l == NL - 1) ? 1 : 0);
    }
}

// Round 11
// 453.113 us; speedup vs baseline: 1.9643x; 1.2153x over previous
//
#include <hip/hip_runtime.h>

#define NN 100000
#define NE 1600000
#define HID 64
#define CH 16                  // channels per chunk
#define NT (NN / 16)           // 16-node MFMA tiles
#define NL 3
#define BN_EPS 1e-5f
#define BSH 7
#define BNODES 128
#define NB 782                 // ceil(NN / BNODES)
#define GP 16                  // global counter pad (ints) -> 64 B/line
#define BIN_CHUNK 8192
#define BIN_GRID ((NE + BIN_CHUNK - 1) / BIN_CHUNK)

typedef __attribute__((ext_vector_type(8))) short short8;
typedef __attribute__((ext_vector_type(4))) float f32x4;

__device__ __forceinline__ float bf2f(unsigned short u) {
    union { unsigned int i; float f; } v; v.i = ((unsigned int)u) << 16; return v.f;
}
__device__ __forceinline__ unsigned short f2bf(float f) {
    union { float f; unsigned int i; } v; v.f = f;
    unsigned int r = v.i + 0x7FFFu + ((v.i >> 16) & 1u);   // RNE
    return (unsigned short)(r >> 16);
}

// ---------------- input convert x f32 -> bf16 chunk-major ----------------
__global__ void k_conv(const float* __restrict__ x, ushort* __restrict__ xc) {
    int i = blockIdx.x * blockDim.x + threadIdx.x;   // over NN*HID/4
    float4 v = ((const float4*)x)[i];
    int node = i >> 4, c4 = (i & 15) * 4;
    int q = c4 >> 4, m = c4 & 15;
    ushort4 o;
    o.x = f2bf(v.x); o.y = f2bf(v.y); o.z = f2bf(v.z); o.w = f2bf(v.w);
    *(ushort4*)(xc + (size_t)q * NN * CH + (size_t)node * CH + m) = o;
}

// ---------------- pack W1/W2 into hi/lo bf16 MFMA B-fragments ----------------
// slot s = layer*4 + {0:W1hi, 1:W1lo, 2:W2hi, 3:W2lo}; frag[(kh*4+t)*64+l][j]
__global__ void k_wpack(const float* __restrict__ W1, const float* __restrict__ W2,
                        ushort* __restrict__ wf) {
    int s = blockIdx.x, l = threadIdx.x;
    int layer = s >> 2, kind = s & 3;
    const float* W = ((kind < 2) ? W1 : W2) + (size_t)layer * HID * HID;
    ushort* o = wf + (size_t)s * 4096;
    for (int kh = 0; kh < 2; ++kh)
        for (int t = 0; t < 4; ++t)
            for (int j = 0; j < 8; ++j) {
                int k = kh * 32 + (l >> 4) * 8 + j;
                int n = t * 16 + (l & 15);
                float f = W[k * HID + n];
                ushort hi = f2bf(f);
                o[((kh * 4 + t) * 64 + l) * 8 + j] =
                    (kind & 1) ? f2bf(f - bf2f(hi)) : hi;
            }
}

// ---------------- bucket histogram: 1024 thr, int4 batch ----------------
__global__ __launch_bounds__(1024) void k_histB(const int* __restrict__ dst,
                                                int* __restrict__ ghist) {
    __shared__ int lh[NB];
    int tid = threadIdx.x;
    for (int i = tid; i < NB; i += 1024) lh[i] = 0;
    __syncthreads();
    int base = blockIdx.x * BIN_CHUNK;
    int end = min(base + BIN_CHUNK, NE);
    for (int e = base + tid * 4; e + 3 < end; e += 4096) {
        int4 d = *(const int4*)(dst + e);
        atomicAdd(&lh[d.x >> BSH], 1);
        atomicAdd(&lh[d.y >> BSH], 1);
        atomicAdd(&lh[d.z >> BSH], 1);
        atomicAdd(&lh[d.w >> BSH], 1);
    }
    __syncthreads();
    for (int i = tid; i < NB; i += 1024)
        if (lh[i]) atomicAdd(&ghist[i * GP], lh[i]);
}

// ---------------- bucket scan (one block, NB <= 1024) ----------------
__global__ void k_scanB(const int* __restrict__ ghist, int* __restrict__ boffB,
                        int* __restrict__ gcur) {
    __shared__ int t[1024];
    int tid = threadIdx.x;
    int v = (tid < NB) ? ghist[tid * GP] : 0;
    t[tid] = v;
    __syncthreads();
    for (int d = 1; d < 1024; d <<= 1) {
        int u = (tid >= d) ? t[tid - d] : 0;
        __syncthreads();
        t[tid] += u;
        __syncthreads();
    }
    if (tid < NB) { int ex = t[tid] - v; boffB[tid] = ex; gcur[tid * GP] = ex; }
    if (tid == 0) boffB[NB] = NE;
}

// ---------------- binning: 1024 thr, 4-edge batch, padded reserve ----------------
__global__ __launch_bounds__(1024) void k_binB(const int* __restrict__ ei,
                                               const float* __restrict__ att,
                                               int* __restrict__ gcur,
                                               int2* __restrict__ evb) {
    __shared__ int lh[NB];
    int tid = threadIdx.x;
    for (int i = tid; i < NB; i += 1024) lh[i] = 0;
    __syncthreads();
    int base = blockIdx.x * BIN_CHUNK;
    int end = min(base + BIN_CHUNK, NE);
    for (int e = base + tid * 4; e + 3 < end; e += 4096) {
        int4 d = *(const int4*)(ei + NE + e);
        atomicAdd(&lh[d.x >> BSH], 1);
        atomicAdd(&lh[d.y >> BSH], 1);
        atomicAdd(&lh[d.z >> BSH], 1);
        atomicAdd(&lh[d.w >> BSH], 1);
    }
    __syncthreads();
    for (int i = tid; i < NB; i += 1024) {
        int c = lh[i];
        lh[i] = c ? atomicAdd(&gcur[i * GP], c) : 0;   // lh becomes running cursor
    }
    __syncthreads();
    for (int e = base + tid * 4; e + 3 < end; e += 4096) {
        int4 s = *(const int4*)(ei + e);
        int4 d = *(const int4*)(ei + NE + e);
        float4 a = *(const float4*)(att + e);
        int p0 = atomicAdd(&lh[d.x >> BSH], 1);
        int p1 = atomicAdd(&lh[d.y >> BSH], 1);
        int p2 = atomicAdd(&lh[d.z >> BSH], 1);
        int p3 = atomicAdd(&lh[d.w >> BSH], 1);
        evb[p0] = make_int2(s.x | ((d.x & (BNODES - 1)) << 17), __float_as_int(a.x));
        evb[p1] = make_int2(s.y | ((d.y & (BNODES - 1)) << 17), __float_as_int(a.y));
        evb[p2] = make_int2(s.z | ((d.z & (BNODES - 1)) << 17), __float_as_int(a.z));
        evb[p3] = make_int2(s.w | ((d.w & (BNODES - 1)) << 17), __float_as_int(a.w));
    }
}

// ------- pass 2: per-bucket CSR placement; compressed 4 B records -------
__global__ __launch_bounds__(256) void k_scatter2(const int2* __restrict__ evb,
                                                  const int* __restrict__ boffB,
                                                  int* __restrict__ offs,
                                                  uint* __restrict__ evc) {
    __shared__ int h[BNODES];
    __shared__ int cur[BNODES];
    int tid = threadIdx.x;
    int b = blockIdx.x;
    int node0 = b << BSH;
    int nvalid = min(BNODES, NN - node0);
    int e0 = boffB[b], e1 = boffB[b + 1];
    if (tid < BNODES) h[tid] = 0;
    __syncthreads();
    for (int e = e0 + tid * 2; e < e1; e += 512) {
        int2 r0 = evb[e];
        int v1 = (e + 1 < e1);
        int2 r1 = evb[v1 ? e + 1 : e];
        atomicAdd(&h[r0.x >> 17], 1);
        if (v1) atomicAdd(&h[r1.x >> 17], 1);
    }
    __syncthreads();
    int v = (tid < BNODES) ? h[tid] : 0;
    for (int d = 1; d < BNODES; d <<= 1) {
        int u = (tid >= d && tid < BNODES) ? h[tid - d] : 0;
        __syncthreads();
        if (tid < BNODES) h[tid] += u;
        __syncthreads();
    }
    if (tid < BNODES) {
        int start = e0 + h[tid] - v;
        cur[tid] = start;
        if (tid < nvalid) offs[node0 + tid] = start;
    }
    if (b == NB - 1 && tid == 0) offs[NN] = NE;
    __syncthreads();
    for (int e = e0 + tid * 2; e < e1; e += 512) {
        int2 r0 = evb[e];
        int v1 = (e + 1 < e1);
        int2 r1 = evb[v1 ? e + 1 : e];
        int p0 = atomicAdd(&cur[r0.x >> 17], 1);
        int p1 = v1 ? atomicAdd(&cur[r1.x >> 17], 1) : 0;
        uint a0 = (uint)(__int_as_float(r0.y) * 32767.0f + 0.5f);
        evc[p0] = ((uint)r0.x & 0x1FFFFu) | (a0 << 17);
        if (v1) {
            uint a1 = (uint)(__int_as_float(r1.y) * 32767.0f + 0.5f);
            evc[p1] = ((uint)r1.x & 0x1FFFFu) | (a1 << 17);
        }
    }
}

// ------- gather: chunk-sharded, 8 slots x 2ch, node-ahead ev prefetch -------
__global__ __launch_bounds__(256, 8) void k_gather(const ushort* __restrict__ xc,
                                                   const int* __restrict__ offs,
                                                   const uint* __restrict__ evc,
                                                   ushort* __restrict__ aggc) {
    int tid = threadIdx.x;
    int wv = tid >> 6, lane = tid & 63;
    int g = lane >> 3;             // edge slot 0..7
    int c2 = lane & 7;             // channel pair (ch = 2*c2, 2*c2+1)
    int q = (blockIdx.x & 7) >> 1;                          // chunk pinned to XCD pair
    int wb = ((blockIdx.x >> 3) << 1) | (blockIdx.x & 1);   // 0..511 within chunk
    const ushort* xq = xc + (size_t)q * NN * CH + c2 * 2;
    ushort* aq = aggc + (size_t)q * NN * CH;
    int slot = wb * 4 + wv;        // 0..2047
    for (int base = slot * 8; base < NN; base += 2048 * 8) {
        uint selfraw = *(const uint*)(xq + (base + g) * CH);      // 256 B coalesced
        int myoff0 = offs[base + c2];
        int myoff1 = offs[base + c2 + 1];
        float rx = 0.f, ry = 0.f;
        int e0n = __shfl(myoff0, 0, 64);
        int e1n = __shfl(myoff1, 0, 64);
        uint evj = evc[min(e0n + g, max(e1n - 1, 0))];            // prefetch j=0
        for (int j = 0; j < 8; ++j) {
            int e0 = e0n, e1 = e1n;
            uint evu = evj;
            if (j < 7) {                                          // prefetch j+1
                e0n = __shfl(myoff0, j + 1, 64);
                e1n = __shfl(myoff1, j + 1, 64);
                evj = evc[min(e0n + g, max(e1n - 1, 0))];
            }
            int e1m1 = max(e1 - 1, 0);
            float ax = 0.f, ay = 0.f;
            for (int e = e0; e < e1; e += 8) {
                uint evn = evc[min(e + 8 + g, e1m1)];             // next-line prefetch
                float a = (e + g < e1) ? (float)(evu >> 17) * (1.0f / 32767.0f) : 0.f;
                int src = evu & 0x1FFFF;
                uint r = *(const uint*)(xq + src * CH);
                union { uint u; float f; } lo, hi;
                lo.u = r << 16; hi.u = r & 0xFFFF0000u;
                ax += lo.f * a; ay += hi.f * a;
                evu = evn;
            }
            ax += __shfl_xor(ax, 8, 64);  ay += __shfl_xor(ay, 8, 64);
            ax += __shfl_xor(ax, 16, 64); ay += __shfl_xor(ay, 16, 64);
            ax += __shfl_xor(ax, 32, 64); ay += __shfl_xor(ay, 32, 64);
            if (g == j) { rx = ax; ry = ay; }
        }
        union { uint u; float f; } sl, sh;
        sl.u = selfraw << 16; sh.u = selfraw & 0xFFFF0000u;
        rx += sl.f; ry += sh.f;                                   // +x (eps=0)
        uint outp = ((uint)f2bf(rx)) | (((uint)f2bf(ry)) << 16);
        *(uint*)(aq + (base + g) * CH + c2 * 2) = outp;           // 256 B store
    }
}

// ------- mlp1 (MFMA): h = agg @ W1 + b1, BN stats; h chunk-major bf16 -------
__global__ __launch_bounds__(256, 2) void k_mlp1(const ushort* __restrict__ aggc,
                                                 const ushort* __restrict__ wfb,
                                                 const float* __restrict__ b1,
                                                 ushort* __restrict__ h,
                                                 float* __restrict__ stats) {
    int tid = threadIdx.x, wv = tid >> 6, l = tid & 63;
    int lg = l >> 4, lc = l & 15;
    short8 bhi[2][4], blo[2][4];
#pragma unroll
    for (int kh = 0; kh < 2; ++kh)
#pragma unroll
        for (int t = 0; t < 4; ++t) {
            bhi[kh][t] = *(const short8*)(wfb + ((kh * 4 + t) * 64 + l) * 8);
            blo[kh][t] = *(const short8*)(wfb + 4096 + ((kh * 4 + t) * 64 + l) * 8);
        }
    float bias[4];
#pragma unroll
    for (int t = 0; t < 4; ++t) bias[t] = b1[t * 16 + lc];
    float s1[4] = {0, 0, 0, 0}, s2[4] = {0, 0, 0, 0};
    int gw = blockIdx.x * 4 + wv, nw = gridDim.x * 4;
    for (int tile = gw; tile < NT; tile += nw) {
        int anode = tile * 16 + lc;               // A row for this lane
        size_t abase = (size_t)(lg >> 1) * NN * CH + (size_t)anode * CH + (lg & 1) * 8;
        short8 a0 = *(const short8*)(aggc + abase);               // k = 0..31
        short8 a1 = *(const short8*)(aggc + abase + 2 * (size_t)NN * CH);  // 32..63
        f32x4 acc[4];
#pragma unroll
        for (int t = 0; t < 4; ++t) {
            acc[t] = (f32x4){bias[t], bias[t], bias[t], bias[t]};
            acc[t] = __builtin_amdgcn_mfma_f32_16x16x32_bf16(a0, bhi[0][t], acc[t], 0, 0, 0);
            acc[t] = __builtin_amdgcn_mfma_f32_16x16x32_bf16(a1, bhi[1][t], acc[t], 0, 0, 0);
            acc[t] = __builtin_amdgcn_mfma_f32_16x16x32_bf16(a0, blo[0][t], acc[t], 0, 0, 0);
            acc[t] = __builtin_amdgcn_mfma_f32_16x16x32_bf16(a1, blo[1][t], acc[t], 0, 0, 0);
        }
#pragma unroll
        for (int t = 0; t < 4; ++t)
#pragma unroll
            for (int r = 0; r < 4; ++r) {
                float d = acc[t][r];
                s1[t] += d; s2[t] += d * d;
                // chunk-major: channel = t*16+lc -> q = t, m = lc
                h[(size_t)t * NN * CH + (size_t)(tile * 16 + lg * 4 + r) * CH + lc] = f2bf(d);
            }
    }
#pragma unroll
    for (int t = 0; t < 4; ++t) {
        s1[t] += __shfl_xor(s1[t], 16, 64); s1[t] += __shfl_xor(s1[t], 32, 64);
        s2[t] += __shfl_xor(s2[t], 16, 64); s2[t] += __shfl_xor(s2[t], 32, 64);
    }
    if (lg == 0)
#pragma unroll
        for (int t = 0; t < 4; ++t) {
            atomicAdd(&stats[t * 16 + lc], s1[t]);
            atomicAdd(&stats[HID + t * 16 + lc], s2[t]);
        }
}

// ------- mlp2 (MFMA): BN -> ReLU -> @W2+b2 -> ReLU; chunk-major bf16 / f32 out -------
__global__ __launch_bounds__(256, 2) void k_mlp2(const ushort* __restrict__ wfb,
                                                 const float* __restrict__ b2,
                                                 const float* __restrict__ gamma,
                                                 const float* __restrict__ beta,
                                                 const float* __restrict__ stats,
                                                 const ushort* __restrict__ h,
                                                 ushort* __restrict__ xc_out,
                                                 float* __restrict__ f_out,
                                                 int write_f32) {
    int tid = threadIdx.x, wv = tid >> 6, l = tid & 63;
    int lg = l >> 4, lc = l & 15;
    short8 bhi[2][4], blo[2][4];
#pragma unroll
    for (int kh = 0; kh < 2; ++kh)
#pragma unroll
        for (int t = 0; t < 4; ++t) {
            bhi[kh][t] = *(const short8*)(wfb + 8192 + ((kh * 4 + t) * 64 + l) * 8);
            blo[kh][t] = *(const short8*)(wfb + 12288 + ((kh * 4 + t) * 64 + l) * 8);
        }
    float bias[4];
#pragma unroll
    for (int t = 0; t < 4; ++t) bias[t] = b2[t * 16 + lc];
    float aCk[2][8], bCk[2][8];                   // BN coeffs for my A channels
#pragma unroll
    for (int kh = 0; kh < 2; ++kh)
#pragma unroll
        for (int j = 0; j < 8; ++j) {
            int k = kh * 32 + lg * 8 + j;
            float mu = stats[k] * (1.0f / NN);
            float var = fmaxf(stats[HID + k] * (1.0f / NN) - mu * mu, 0.f);
            float aC = gamma[k] * rsqrtf(var + BN_EPS);
            aCk[kh][j] = aC;
            bCk[kh][j] = beta[k] - mu * aC;
        }
    int gw = blockIdx.x * 4 + wv, nw = gridDim.x * 4;
    for (int tile = gw; tile < NT; tile += nw) {
        int anode = tile * 16 + lc;
        size_t abase = (size_t)(lg >> 1) * NN * CH + (size_t)anode * CH + (lg & 1) * 8;
        short8 a0r = *(const short8*)(h + abase);
        short8 a1r = *(const short8*)(h + abase + 2 * (size_t)NN * CH);
        short8 a0, a1;
#pragma unroll
        for (int j = 0; j < 8; ++j) {
            float v0 = fmaxf(aCk[0][j] * bf2f((ushort)a0r[j]) + bCk[0][j], 0.f);
            float v1 = fmaxf(aCk[1][j] * bf2f((ushort)a1r[j]) + bCk[1][j], 0.f);
            a0[j] = (short)f2bf(v0);
            a1[j] = (short)f2bf(v1);
        }
        f32x4 acc[4];
#pragma unroll
        for (int t = 0; t < 4; ++t) {
            acc[t] = (f32x4){bias[t], bias[t], bias[t], bias[t]};
            acc[t] = __builtin_amdgcn_mfma_f32_16x16x32_bf16(a0, bhi[0][t], acc[t], 0, 0, 0);
            acc[t] = __builtin_amdgcn_mfma_f32_16x16x32_bf16(a1, bhi[1][t], acc[t], 0, 0, 0);
            acc[t] = __builtin_amdgcn_mfma_f32_16x16x32_bf16(a0, blo[0][t], acc[t], 0, 0, 0);
            acc[t] = __builtin_amdgcn_mfma_f32_16x16x32_bf16(a1, blo[1][t], acc[t], 0, 0, 0);
        }
#pragma unroll
        for (int t = 0; t < 4; ++t)
#pragma unroll
            for (int r = 0; r < 4; ++r) {
                float d = fmaxf(acc[t][r], 0.f);
                int node = tile * 16 + lg * 4 + r;
                if (write_f32) f_out[(size_t)node * HID + t * 16 + lc] = d;
                else xc_out[(size_t)t * NN * CH + (size_t)node * CH + lc] = f2bf(d);
            }
    }
}

extern "C" void kernel_launch(void* const* d_in, const int* in_sizes, int n_in,
                              void* d_out, int out_size, void* d_ws, size_t ws_size,
                              hipStream_t stream) {
    const float* x_in  = (const float*)d_in[0];
    const int*   ei    = (const int*)d_in[1];
    const float* att   = (const float*)d_in[2];
    const float* W1    = (const float*)d_in[3];
    const float* b1    = (const float*)d_in[4];
    const float* gamma = (const float*)d_in[5];
    const float* beta  = (const float*)d_in[6];
    const float* W2    = (const float*)d_in[7];
    const float* b2    = (const float*)d_in[8];
    float* out = (float*)d_out;

    char* ws = (char*)d_ws;
    size_t off = 0;
    auto alloc = [&](size_t bytes) -> void* {
        void* p = ws + off;
        off += (bytes + 255) & ~(size_t)255;
        return p;
    };
    ushort* xc    = (ushort*)alloc((size_t)NN * HID * 2);   // chunk-major x
    ushort* aggc  = (ushort*)alloc((size_t)NN * HID * 2);   // chunk-major agg
    ushort* hb    = (ushort*)alloc((size_t)NN * HID * 2);   // chunk-major h
    ushort* wf    = (ushort*)alloc((size_t)12 * 4096 * 2);  // W fragments hi/lo
    int*    ghist = (int*)alloc((size_t)NB * GP * 4);
    int*    boffB = (int*)alloc((size_t)(NB + 1) * 4);
    int*    gcur  = (int*)alloc((size_t)NB * GP * 4);
    int*    offs  = (int*)alloc((size_t)(NN + 1) * 4);
    int2*   evb   = (int2*)alloc((size_t)NE * 8);
    uint*   evc   = (uint*)alloc((size_t)NE * 4);           // compressed records
    float*  stats = (float*)alloc(NL * 128 * 4);

    hipMemsetAsync(ghist, 0, (size_t)NB * GP * 4, stream);
    hipMemsetAsync(stats, 0, NL * 128 * 4, stream);

    k_conv<<<(NN * HID / 4 + 255) / 256, 256, 0, stream>>>(x_in, xc);
    k_wpack<<<12, 64, 0, stream>>>(W1, W2, wf);
    k_histB<<<BIN_GRID, 1024, 0, stream>>>(ei + NE, ghist);
    k_scanB<<<1, 1024, 0, stream>>>(ghist, boffB, gcur);
    k_binB<<<BIN_GRID, 1024, 0, stream>>>(ei, att, gcur, evb);
    k_scatter2<<<NB, 256, 0, stream>>>(evb, boffB, offs, evc);

    for (int l = 0; l < NL; ++l) {
        const ushort* wfb = wf + (size_t)l * 4 * 4096;
        k_gather<<<2048, 256, 0, stream>>>(xc, offs, evc, aggc);
        k_mlp1<<<512, 256, 0, stream>>>(aggc, wfb, b1 + l * HID, hb, stats + l * 128);
        k_mlp2<<<512, 256, 0, stream>>>(wfb, b2 + l * HID,
                                        gamma + l * HID, beta + l * HID,
                                        stats + l * 128, hb,
                                        xc, out, (l == NL - 1) ? 1 : 0);
    }
}

// Round 12
// 391.101 us; speedup vs baseline: 2.2758x; 1.1586x over previous
//
#include <hip/hip_runtime.h>

#define NN 100000
#define NE 1600000
#define HID 64
#define CH 32                  // channels per chunk (2 chunks of 6.4 MB)
#define NT (NN / 16)           // 16-node MFMA tiles
#define NL 3
#define BN_EPS 1e-5f
#define BSH 7
#define BNODES 128
#define NB 782                 // ceil(NN / BNODES)
#define GP 16                  // global counter pad (ints) -> 64 B/line
#define BIN_CHUNK 8192
#define BIN_GRID ((NE + BIN_CHUNK - 1) / BIN_CHUNK)

typedef __attribute__((ext_vector_type(8))) short short8;
typedef __attribute__((ext_vector_type(4))) float f32x4;

__device__ __forceinline__ float bf2f(unsigned short u) {
    union { unsigned int i; float f; } v; v.i = ((unsigned int)u) << 16; return v.f;
}
__device__ __forceinline__ unsigned short f2bf(float f) {
    union { float f; unsigned int i; } v; v.f = f;
    unsigned int r = v.i + 0x7FFFu + ((v.i >> 16) & 1u);   // RNE
    return (unsigned short)(r >> 16);
}

// ---------------- input convert x f32 -> bf16 chunk-major (CH=32) ----------------
__global__ void k_conv(const float* __restrict__ x, ushort* __restrict__ xc) {
    int i = blockIdx.x * blockDim.x + threadIdx.x;   // over NN*HID/4
    float4 v = ((const float4*)x)[i];
    int node = i >> 4, c4 = (i & 15) * 4;
    int q = c4 >> 5, m = c4 & 31;
    ushort4 o;
    o.x = f2bf(v.x); o.y = f2bf(v.y); o.z = f2bf(v.z); o.w = f2bf(v.w);
    *(ushort4*)(xc + (size_t)q * NN * CH + (size_t)node * CH + m) = o;
}

// ---------------- pack W1/W2 into hi/lo bf16 MFMA fragments ----------------
// slot s = layer*4 + {0:W1hi, 1:W1lo, 2:W2hi, 3:W2lo}; frag[(kh*4+t)*64+l][j]
__global__ void k_wpack(const float* __restrict__ W1, const float* __restrict__ W2,
                        ushort* __restrict__ wf) {
    int s = blockIdx.x, l = threadIdx.x;
    int layer = s >> 2, kind = s & 3;
    const float* W = ((kind < 2) ? W1 : W2) + (size_t)layer * HID * HID;
    ushort* o = wf + (size_t)s * 4096;
    for (int kh = 0; kh < 2; ++kh)
        for (int t = 0; t < 4; ++t)
            for (int j = 0; j < 8; ++j) {
                int k = kh * 32 + (l >> 4) * 8 + j;
                int n = t * 16 + (l & 15);
                float f = W[k * HID + n];
                ushort hi = f2bf(f);
                o[((kh * 4 + t) * 64 + l) * 8 + j] =
                    (kind & 1) ? f2bf(f - bf2f(hi)) : hi;
            }
}

// ---------------- bucket histogram: 1024 thr, int4 batch ----------------
__global__ __launch_bounds__(1024) void k_histB(const int* __restrict__ dst,
                                                int* __restrict__ ghist) {
    __shared__ int lh[NB];
    int tid = threadIdx.x;
    for (int i = tid; i < NB; i += 1024) lh[i] = 0;
    __syncthreads();
    int base = blockIdx.x * BIN_CHUNK;
    int end = min(base + BIN_CHUNK, NE);
    for (int e = base + tid * 4; e + 3 < end; e += 4096) {
        int4 d = *(const int4*)(dst + e);
        atomicAdd(&lh[d.x >> BSH], 1);
        atomicAdd(&lh[d.y >> BSH], 1);
        atomicAdd(&lh[d.z >> BSH], 1);
        atomicAdd(&lh[d.w >> BSH], 1);
    }
    __syncthreads();
    for (int i = tid; i < NB; i += 1024)
        if (lh[i]) atomicAdd(&ghist[i * GP], lh[i]);
}

// ---------------- bucket scan (one block, NB <= 1024) ----------------
__global__ void k_scanB(const int* __restrict__ ghist, int* __restrict__ boffB,
                        int* __restrict__ gcur) {
    __shared__ int t[1024];
    int tid = threadIdx.x;
    int v = (tid < NB) ? ghist[tid * GP] : 0;
    t[tid] = v;
    __syncthreads();
    for (int d = 1; d < 1024; d <<= 1) {
        int u = (tid >= d) ? t[tid - d] : 0;
        __syncthreads();
        t[tid] += u;
        __syncthreads();
    }
    if (tid < NB) { int ex = t[tid] - v; boffB[tid] = ex; gcur[tid * GP] = ex; }
    if (tid == 0) boffB[NB] = NE;
}

// ---------------- binning: 1024 thr, 4-edge batch, padded reserve ----------------
__global__ __launch_bounds__(1024) void k_binB(const int* __restrict__ ei,
                                               const float* __restrict__ att,
                                               int* __restrict__ gcur,
                                               int2* __restrict__ evb) {
    __shared__ int lh[NB];
    int tid = threadIdx.x;
    for (int i = tid; i < NB; i += 1024) lh[i] = 0;
    __syncthreads();
    int base = blockIdx.x * BIN_CHUNK;
    int end = min(base + BIN_CHUNK, NE);
    for (int e = base + tid * 4; e + 3 < end; e += 4096) {
        int4 d = *(const int4*)(ei + NE + e);
        atomicAdd(&lh[d.x >> BSH], 1);
        atomicAdd(&lh[d.y >> BSH], 1);
        atomicAdd(&lh[d.z >> BSH], 1);
        atomicAdd(&lh[d.w >> BSH], 1);
    }
    __syncthreads();
    for (int i = tid; i < NB; i += 1024) {
        int c = lh[i];
        lh[i] = c ? atomicAdd(&gcur[i * GP], c) : 0;   // lh becomes running cursor
    }
    __syncthreads();
    for (int e = base + tid * 4; e + 3 < end; e += 4096) {
        int4 s = *(const int4*)(ei + e);
        int4 d = *(const int4*)(ei + NE + e);
        float4 a = *(const float4*)(att + e);
        int p0 = atomicAdd(&lh[d.x >> BSH], 1);
        int p1 = atomicAdd(&lh[d.y >> BSH], 1);
        int p2 = atomicAdd(&lh[d.z >> BSH], 1);
        int p3 = atomicAdd(&lh[d.w >> BSH], 1);
        evb[p0] = make_int2(s.x | ((d.x & (BNODES - 1)) << 17), __float_as_int(a.x));
        evb[p1] = make_int2(s.y | ((d.y & (BNODES - 1)) << 17), __float_as_int(a.y));
        evb[p2] = make_int2(s.z | ((d.z & (BNODES - 1)) << 17), __float_as_int(a.z));
        evb[p3] = make_int2(s.w | ((d.w & (BNODES - 1)) << 17), __float_as_int(a.w));
    }
}

// ------- pass 2: per-bucket CSR placement; compressed 4 B records -------
__global__ __launch_bounds__(256) void k_scatter2(const int2* __restrict__ evb,
                                                  const int* __restrict__ boffB,
                                                  int* __restrict__ offs,
                                                  uint* __restrict__ evc) {
    __shared__ int h[BNODES];
    __shared__ int cur[BNODES];
    int tid = threadIdx.x;
    int b = blockIdx.x;
    int node0 = b << BSH;
    int nvalid = min(BNODES, NN - node0);
    int e0 = boffB[b], e1 = boffB[b + 1];
    if (tid < BNODES) h[tid] = 0;
    __syncthreads();
    for (int e = e0 + tid * 2; e < e1; e += 512) {
        int2 r0 = evb[e];
        int v1 = (e + 1 < e1);
        int2 r1 = evb[v1 ? e + 1 : e];
        atomicAdd(&h[r0.x >> 17], 1);
        if (v1) atomicAdd(&h[r1.x >> 17], 1);
    }
    __syncthreads();
    int v = (tid < BNODES) ? h[tid] : 0;
    for (int d = 1; d < BNODES; d <<= 1) {
        int u = (tid >= d && tid < BNODES) ? h[tid - d] : 0;
        __syncthreads();
        if (tid < BNODES) h[tid] += u;
        __syncthreads();
    }
    if (tid < BNODES) {
        int start = e0 + h[tid] - v;
        cur[tid] = start;
        if (tid < nvalid) offs[node0 + tid] = start;
    }
    if (b == NB - 1 && tid == 0) offs[NN] = NE;
    __syncthreads();
    for (int e = e0 + tid * 2; e < e1; e += 512) {
        int2 r0 = evb[e];
        int v1 = (e + 1 < e1);
        int2 r1 = evb[v1 ? e + 1 : e];
        int p0 = atomicAdd(&cur[r0.x >> 17], 1);
        int p1 = v1 ? atomicAdd(&cur[r1.x >> 17], 1) : 0;
        uint a0 = (uint)(__int_as_float(r0.y) * 32767.0f + 0.5f);
        evc[p0] = ((uint)r0.x & 0x1FFFFu) | (a0 << 17);
        if (v1) {
            uint a1 = (uint)(__int_as_float(r1.y) * 32767.0f + 0.5f);
            evc[p1] = ((uint)r1.x & 0x1FFFFu) | (a1 << 17);
        }
    }
}

// ------- gather: CH=32, 4 slots x 16 ch-pairs, 8 nodes/sweep, ev prefetch -------
__global__ __launch_bounds__(256, 8) void k_gather(const ushort* __restrict__ xc,
                                                   const int* __restrict__ offs,
                                                   const uint* __restrict__ evc,
                                                   ushort* __restrict__ aggc) {
    int tid = threadIdx.x;
    int wv = tid >> 6, lane = tid & 63;
    int g = lane >> 4;              // edge slot 0..3
    int c2 = lane & 15;             // channel pair 0..15 (ch = 2*c2, 2*c2+1)
    int q = (blockIdx.x & 7) >> 2;                          // chunk pinned to XCD quad
    int wb = ((blockIdx.x >> 3) << 2) | (blockIdx.x & 3);   // 0..1023 within chunk
    const ushort* xq = xc + (size_t)q * NN * CH + c2 * 2;
    ushort* aq = aggc + (size_t)q * NN * CH;
    int slot = wb * 4 + wv;         // 0..4095
    for (int base = slot * 8; base < NN; base += 4096 * 8) {
        uint self0 = *(const uint*)(xq + (base + g) * CH);        // coalesced
        uint self1 = *(const uint*)(xq + (base + g + 4) * CH);
        int myoff = offs[min(base + c2, NN)];
        float rx0 = 0.f, ry0 = 0.f, rx1 = 0.f, ry1 = 0.f;
        int e0n = __shfl(myoff, 0, 64);
        int e1n = __shfl(myoff, 1, 64);
        uint evj = evc[min(e0n + g, max(e1n - 1, 0))];            // prefetch j=0
        for (int j = 0; j < 8; ++j) {
            int e0 = e0n, e1 = e1n;
            uint evu = evj;
            if (j < 7) {                                          // prefetch j+1
                e0n = __shfl(myoff, j + 1, 64);
                e1n = __shfl(myoff, j + 2, 64);
                evj = evc[min(e0n + g, max(e1n - 1, 0))];
            }
            int e1m1 = max(e1 - 1, 0);
            float ax = 0.f, ay = 0.f;
            for (int e = e0; e < e1; e += 4) {
                uint evn = evc[min(e + 4 + g, e1m1)];             // next-batch prefetch
                float a = (e + g < e1) ? (float)(evu >> 17) * (1.0f / 32767.0f) : 0.f;
                uint r = *(const uint*)(xq + (evu & 0x1FFFF) * CH);  // 64 B line/edge
                union { uint u; float f; } lo, hi;
                lo.u = r << 16; hi.u = r & 0xFFFF0000u;
                ax += lo.f * a; ay += hi.f * a;
                evu = evn;
            }
            ax += __shfl_xor(ax, 16, 64); ax += __shfl_xor(ax, 32, 64);
            ay += __shfl_xor(ay, 16, 64); ay += __shfl_xor(ay, 32, 64);
            if (j == g)     { rx0 = ax; ry0 = ay; }
            if (j == g + 4) { rx1 = ax; ry1 = ay; }
        }
        union { uint u; float f; } s;
        s.u = self0 << 16;         rx0 += s.f;                    // +x (eps=0)
        s.u = self0 & 0xFFFF0000u; ry0 += s.f;
        s.u = self1 << 16;         rx1 += s.f;
        s.u = self1 & 0xFFFF0000u; ry1 += s.f;
        uint o0 = ((uint)f2bf(rx0)) | (((uint)f2bf(ry0)) << 16);
        uint o1 = ((uint)f2bf(rx1)) | (((uint)f2bf(ry1)) << 16);
        *(uint*)(aq + (base + g) * CH + c2 * 2) = o0;             // 256 B stores
        *(uint*)(aq + (base + g + 4) * CH + c2 * 2) = o1;
    }
}

// ------- mlp1 (MFMA, C^T): h = agg @ W1 + b1, BN stats; vectorized stores -------
__global__ __launch_bounds__(256, 2) void k_mlp1(const ushort* __restrict__ aggc,
                                                 const ushort* __restrict__ wfb,
                                                 const float* __restrict__ b1,
                                                 ushort* __restrict__ h,
                                                 float* __restrict__ stats) {
    __shared__ float red1[4][64], red2[4][64];
    int tid = threadIdx.x, wv = tid >> 6, l = tid & 63;
    int lg = l >> 4, lc = l & 15;
    short8 bhi[2][4], blo[2][4];
#pragma unroll
    for (int kh = 0; kh < 2; ++kh)
#pragma unroll
        for (int t = 0; t < 4; ++t) {
            bhi[kh][t] = *(const short8*)(wfb + ((kh * 4 + t) * 64 + l) * 8);
            blo[kh][t] = *(const short8*)(wfb + 4096 + ((kh * 4 + t) * 64 + l) * 8);
        }
    f32x4 bias4[4];
#pragma unroll
    for (int t = 0; t < 4; ++t) {
        float4 bv = *(const float4*)(b1 + t * 16 + lg * 4);
        bias4[t] = (f32x4){bv.x, bv.y, bv.z, bv.w};
    }
    float s1[16], s2[16];
#pragma unroll
    for (int i = 0; i < 16; ++i) { s1[i] = 0.f; s2[i] = 0.f; }
    int gw = blockIdx.x * 4 + wv, nw = gridDim.x * 4;
    for (int tile = gw; tile < NT; tile += nw) {
        int node = tile * 16 + lc;
        const ushort* ap = aggc + (size_t)node * CH + lg * 8;
        short8 a0 = *(const short8*)ap;                           // ch 0..31
        short8 a1 = *(const short8*)(ap + (size_t)NN * CH);       // ch 32..63
        f32x4 acc[4];
#pragma unroll
        for (int t = 0; t < 4; ++t) {
            acc[t] = bias4[t];
            acc[t] = __builtin_amdgcn_mfma_f32_16x16x32_bf16(bhi[0][t], a0, acc[t], 0, 0, 0);
            acc[t] = __builtin_amdgcn_mfma_f32_16x16x32_bf16(bhi[1][t], a1, acc[t], 0, 0, 0);
            acc[t] = __builtin_amdgcn_mfma_f32_16x16x32_bf16(blo[0][t], a0, acc[t], 0, 0, 0);
            acc[t] = __builtin_amdgcn_mfma_f32_16x16x32_bf16(blo[1][t], a1, acc[t], 0, 0, 0);
        }
#pragma unroll
        for (int t = 0; t < 4; ++t) {
            ushort4 o;
            float d0 = acc[t][0], d1 = acc[t][1], d2 = acc[t][2], d3 = acc[t][3];
            s1[t * 4 + 0] += d0; s2[t * 4 + 0] += d0 * d0;
            s1[t * 4 + 1] += d1; s2[t * 4 + 1] += d1 * d1;
            s1[t * 4 + 2] += d2; s2[t * 4 + 2] += d2 * d2;
            s1[t * 4 + 3] += d3; s2[t * 4 + 3] += d3 * d3;
            o.x = f2bf(d0); o.y = f2bf(d1); o.z = f2bf(d2); o.w = f2bf(d3);
            *(ushort4*)(h + (size_t)(t >> 1) * NN * CH + (size_t)node * CH
                        + (t & 1) * 16 + lg * 4) = o;
        }
    }
#pragma unroll
    for (int i = 0; i < 16; ++i) {
        s1[i] += __shfl_xor(s1[i], 1, 64); s1[i] += __shfl_xor(s1[i], 2, 64);
        s1[i] += __shfl_xor(s1[i], 4, 64); s1[i] += __shfl_xor(s1[i], 8, 64);
        s2[i] += __shfl_xor(s2[i], 1, 64); s2[i] += __shfl_xor(s2[i], 2, 64);
        s2[i] += __shfl_xor(s2[i], 4, 64); s2[i] += __shfl_xor(s2[i], 8, 64);
    }
    if (lc == 0) {
#pragma unroll
        for (int t = 0; t < 4; ++t)
#pragma unroll
            for (int r = 0; r < 4; ++r) {
                red1[wv][t * 16 + lg * 4 + r] = s1[t * 4 + r];
                red2[wv][t * 16 + lg * 4 + r] = s2[t * 4 + r];
            }
    }
    __syncthreads();
    if (tid < 64)
        atomicAdd(&stats[tid], red1[0][tid] + red1[1][tid] + red1[2][tid] + red1[3][tid]);
    else if (tid < 128) {
        int c = tid - 64;
        atomicAdd(&stats[HID + c], red2[0][c] + red2[1][c] + red2[2][c] + red2[3][c]);
    }
}

// ------- mlp2 (MFMA, C^T): BN -> ReLU -> @W2+b2 -> ReLU; vectorized stores -------
__global__ __launch_bounds__(256, 2) void k_mlp2(const ushort* __restrict__ wfb,
                                                 const float* __restrict__ b2,
                                                 const float* __restrict__ gamma,
                                                 const float* __restrict__ beta,
                                                 const float* __restrict__ stats,
                                                 const ushort* __restrict__ h,
                                                 ushort* __restrict__ xc_out,
                                                 float* __restrict__ f_out,
                                                 int write_f32) {
    int tid = threadIdx.x, wv = tid >> 6, l = tid & 63;
    int lg = l >> 4, lc = l & 15;
    short8 bhi[2][4], blo[2][4];
#pragma unroll
    for (int kh = 0; kh < 2; ++kh)
#pragma unroll
        for (int t = 0; t < 4; ++t) {
            bhi[kh][t] = *(const short8*)(wfb + 8192 + ((kh * 4 + t) * 64 + l) * 8);
            blo[kh][t] = *(const short8*)(wfb + 12288 + ((kh * 4 + t) * 64 + l) * 8);
        }
    f32x4 bias4[4];
#pragma unroll
    for (int t = 0; t < 4; ++t) {
        float4 bv = *(const float4*)(b2 + t * 16 + lg * 4);
        bias4[t] = (f32x4){bv.x, bv.y, bv.z, bv.w};
    }
    float aCk[2][8], bCk[2][8];
#pragma unroll
    for (int kh = 0; kh < 2; ++kh)
#pragma unroll
        for (int j = 0; j < 8; ++j) {
            int k = kh * 32 + lg * 8 + j;
            float mu = stats[k] * (1.0f / NN);
            float var = fmaxf(stats[HID + k] * (1.0f / NN) - mu * mu, 0.f);
            float aC = gamma[k] * rsqrtf(var + BN_EPS);
            aCk[kh][j] = aC;
            bCk[kh][j] = beta[k] - mu * aC;
        }
    int gw = blockIdx.x * 4 + wv, nw = gridDim.x * 4;
    for (int tile = gw; tile < NT; tile += nw) {
        int node = tile * 16 + lc;
        const ushort* hp = h + (size_t)node * CH + lg * 8;
        short8 a0r = *(const short8*)hp;
        short8 a1r = *(const short8*)(hp + (size_t)NN * CH);
        short8 a0, a1;
#pragma unroll
        for (int j = 0; j < 8; ++j) {
            float v0 = fmaxf(aCk[0][j] * bf2f((ushort)a0r[j]) + bCk[0][j], 0.f);
            float v1 = fmaxf(aCk[1][j] * bf2f((ushort)a1r[j]) + bCk[1][j], 0.f);
            a0[j] = (short)f2bf(v0);
            a1[j] = (short)f2bf(v1);
        }
        f32x4 acc[4];
#pragma unroll
        for (int t = 0; t < 4; ++t) {
            acc[t] = bias4[t];
            acc[t] = __builtin_amdgcn_mfma_f32_16x16x32_bf16(bhi[0][t], a0, acc[t], 0, 0, 0);
            acc[t] = __builtin_amdgcn_mfma_f32_16x16x32_bf16(bhi[1][t], a1, acc[t], 0, 0, 0);
            acc[t] = __builtin_amdgcn_mfma_f32_16x16x32_bf16(blo[0][t], a0, acc[t], 0, 0, 0);
            acc[t] = __builtin_amdgcn_mfma_f32_16x16x32_bf16(blo[1][t], a1, acc[t], 0, 0, 0);
        }
        if (write_f32) {
#pragma unroll
            for (int t = 0; t < 4; ++t) {
                float4 o4;
                o4.x = fmaxf(acc[t][0], 0.f); o4.y = fmaxf(acc[t][1], 0.f);
                o4.z = fmaxf(acc[t][2], 0.f); o4.w = fmaxf(acc[t][3], 0.f);
                *(float4*)(f_out + (size_t)node * HID + t * 16 + lg * 4) = o4;
            }
        } else {
#pragma unroll
            for (int t = 0; t < 4; ++t) {
                ushort4 o;
                o.x = f2bf(fmaxf(acc[t][0], 0.f)); o.y = f2bf(fmaxf(acc[t][1], 0.f));
                o.z = f2bf(fmaxf(acc[t][2], 0.f)); o.w = f2bf(fmaxf(acc[t][3], 0.f));
                *(ushort4*)(xc_out + (size_t)(t >> 1) * NN * CH + (size_t)node * CH
                            + (t & 1) * 16 + lg * 4) = o;
            }
        }
    }
}

extern "C" void kernel_launch(void* const* d_in, const int* in_sizes, int n_in,
                              void* d_out, int out_size, void* d_ws, size_t ws_size,
                              hipStream_t stream) {
    const float* x_in  = (const float*)d_in[0];
    const int*   ei    = (const int*)d_in[1];
    const float* att   = (const float*)d_in[2];
    const float* W1    = (const float*)d_in[3];
    const float* b1    = (const float*)d_in[4];
    const float* gamma = (const float*)d_in[5];
    const float* beta  = (const float*)d_in[6];
    const float* W2    = (const float*)d_in[7];
    const float* b2    = (const float*)d_in[8];
    float* out = (float*)d_out;

    char* ws = (char*)d_ws;
    size_t off = 0;
    auto alloc = [&](size_t bytes) -> void* {
        void* p = ws + off;
        off += (bytes + 255) & ~(size_t)255;
        return p;
    };
    ushort* xc    = (ushort*)alloc((size_t)NN * HID * 2);   // chunk-major x
    ushort* aggc  = (ushort*)alloc((size_t)NN * HID * 2);   // chunk-major agg
    ushort* hb    = (ushort*)alloc((size_t)NN * HID * 2);   // chunk-major h
    ushort* wf    = (ushort*)alloc((size_t)12 * 4096 * 2);  // W fragments hi/lo
    int*    ghist = (int*)alloc((size_t)NB * GP * 4);
    int*    boffB = (int*)alloc((size_t)(NB + 1) * 4);
    int*    gcur  = (int*)alloc((size_t)NB * GP * 4);
    int*    offs  = (int*)alloc((size_t)(NN + 1) * 4);
    int2*   evb   = (int2*)alloc((size_t)NE * 8);
    uint*   evc   = (uint*)alloc((size_t)NE * 4);           // compressed records
    float*  stats = (float*)alloc(NL * 128 * 4);

    hipMemsetAsync(ghist, 0, (size_t)NB * GP * 4, stream);
    hipMemsetAsync(stats, 0, NL * 128 * 4, stream);

    k_conv<<<(NN * HID / 4 + 255) / 256, 256, 0, stream>>>(x_in, xc);
    k_wpack<<<12, 64, 0, stream>>>(W1, W2, wf);
    k_histB<<<BIN_GRID, 1024, 0, stream>>>(ei + NE, ghist);
    k_scanB<<<1, 1024, 0, stream>>>(ghist, boffB, gcur);
    k_binB<<<BIN_GRID, 1024, 0, stream>>>(ei, att, gcur, evb);
    k_scatter2<<<NB, 256, 0, stream>>>(evb, boffB, offs, evc);

    for (int l = 0; l < NL; ++l) {
        const ushort* wfb = wf + (size_t)l * 4 * 4096;
        k_gather<<<2048, 256, 0, stream>>>(xc, offs, evc, aggc);
        k_mlp1<<<1024, 256, 0, stream>>>(aggc, wfb, b1 + l * HID, hb, stats + l * 128);
        k_mlp2<<<1024, 256, 0, stream>>>(wfb, b2 + l * HID,
                                         gamma + l * HID, beta + l * HID,
                                         stats + l * 128, hb,
                                         xc, out, (l == NL - 1) ? 1 : 0);
    }
}